// Round 1
// baseline (2986.619 us; speedup 1.0000x reference)
//
#include <hip/hip_runtime.h>
#include <hip/hip_bf16.h>
#include <math.h>

#define BB 4
#define TT 4096
#define DD 2048
#define HH 16
#define HDIM 128
#define KSEL 512
#define NBH (BB*HH)

// ---------------- K1: router scores [B,H,T] ----------------
__global__ __launch_bounds__(256) void k_router(const float* __restrict__ x,
                                                const float* __restrict__ wr,
                                                float* __restrict__ scores) {
  int wave = threadIdx.x >> 6, lane = threadIdx.x & 63;
  int row = blockIdx.x * 4 + wave;          // b*T + t
  int b = row >> 12, t = row & (TT - 1);
  const float* xr = x + (size_t)row * DD;
  float xi[32];
#pragma unroll
  for (int i = 0; i < 32; ++i) xi[i] = xr[lane + i * 64];
  for (int h = 0; h < HH; ++h) {
    const float* w = wr + (size_t)h * DD;
    float acc = 0.f;
#pragma unroll
    for (int i = 0; i < 32; ++i) acc += xi[i] * w[lane + i * 64];
#pragma unroll
    for (int off = 32; off; off >>= 1) acc += __shfl_xor(acc, off);
    if (lane == 0) scores[((size_t)(b * HH + h)) * TT + t] = acc;
  }
}

// ---------------- K2: per-(b,h) top-512, output ascending by position ----------------
__global__ __launch_bounds__(512) void k_topk(const float* __restrict__ scores,
                                              int* __restrict__ idx) {
  __shared__ unsigned long long keys[TT];
  __shared__ unsigned tsel[KSEL];
  int bh = blockIdx.x, tid = threadIdx.x;
  const float* sc = scores + (size_t)bh * TT;
  for (int i = tid; i < TT; i += 512) {
    unsigned u = __float_as_uint(sc[i]);
    u = (u & 0x80000000u) ? ~u : (u | 0x80000000u);  // monotone map
    keys[i] = ((unsigned long long)u << 32) | (unsigned)(~i); // tie: lower i wins
  }
  __syncthreads();
  for (int k = 2; k <= TT; k <<= 1)
    for (int j = k >> 1; j > 0; j >>= 1) {
      for (int i = tid; i < TT; i += 512) {
        int ixj = i ^ j;
        if (ixj > i) {
          unsigned long long a = keys[i], c = keys[ixj];
          bool asc = ((i & k) == 0);
          if (asc ? (a > c) : (a < c)) { keys[i] = c; keys[ixj] = a; }
        }
      }
      __syncthreads();
    }
  // largest 512 keys sit at the top; recover t = ~(low 32 bits)
  if (tid < KSEL) tsel[tid] = ~((unsigned)keys[TT - KSEL + tid]);
  __syncthreads();
  for (int k = 2; k <= KSEL; k <<= 1)
    for (int j = k >> 1; j > 0; j >>= 1) {
      int i = tid, ixj = tid ^ j;
      if (ixj > i) {
        unsigned a = tsel[i], c = tsel[ixj];
        bool asc = ((i & k) == 0);
        if (asc ? (a > c) : (a < c)) { tsel[i] = c; tsel[ixj] = a; }
      }
      __syncthreads();
    }
  if (tid < KSEL) idx[bh * KSEL + tid] = (int)tsel[tid];
}

// ---------------- K3: gathered QKV projections [bh,512,128] ----------------
__global__ __launch_bounds__(256) void k_qkv(const float* __restrict__ x,
    const float* __restrict__ wq, const float* __restrict__ wk,
    const float* __restrict__ wv, const int* __restrict__ idx,
    float* __restrict__ q_s, float* __restrict__ k_s, float* __restrict__ v_s) {
  __shared__ __align__(16) float xT[32][36];
  __shared__ __align__(16) float wqT[32][132];
  __shared__ __align__(16) float wkT[32][132];
  __shared__ __align__(16) float wvT[32][132];
  __shared__ int tIdx[32];
  int bh = blockIdx.x, rt = blockIdx.y;
  int b = bh >> 4, h = bh & 15;
  int tid = threadIdx.x;
  if (tid < 32) tIdx[tid] = idx[bh * KSEL + rt * 32 + tid];
  int rg = tid & 7, cg = tid >> 3;  // 4 rows (rg*4..), 4 cols (cg*4..)
  float accq[16], acck[16], accv[16];
#pragma unroll
  for (int i = 0; i < 16; ++i) { accq[i]=0.f; acck[i]=0.f; accv[i]=0.f; }
  for (int c0 = 0; c0 < DD; c0 += 32) {
    __syncthreads();
    int kk = tid & 31;
    for (int rr = tid >> 5; rr < 32; rr += 8) {
      int t = tIdx[rr];
      xT[kk][rr] = x[((size_t)(b * TT + t)) * DD + c0 + kk];
    }
    for (int cc = tid >> 5; cc < 128; cc += 8) {
      size_t off = ((size_t)(h * HDIM + cc)) * DD + c0 + kk;
      wqT[kk][cc] = wq[off];
      wkT[kk][cc] = wk[off];
      wvT[kk][cc] = wv[off];
    }
    __syncthreads();
#pragma unroll 8
    for (int k2 = 0; k2 < 32; ++k2) {
      float4 a4 = *(const float4*)&xT[k2][rg * 4];
      float4 q4 = *(const float4*)&wqT[k2][cg * 4];
      float4 kw4 = *(const float4*)&wkT[k2][cg * 4];
      float4 v4 = *(const float4*)&wvT[k2][cg * 4];
      float av[4] = {a4.x, a4.y, a4.z, a4.w};
      float qv[4] = {q4.x, q4.y, q4.z, q4.w};
      float kv[4] = {kw4.x, kw4.y, kw4.z, kw4.w};
      float vv[4] = {v4.x, v4.y, v4.z, v4.w};
#pragma unroll
      for (int i = 0; i < 4; ++i)
#pragma unroll
        for (int j = 0; j < 4; ++j) {
          accq[i*4+j] += av[i] * qv[j];
          acck[i*4+j] += av[i] * kv[j];
          accv[i*4+j] += av[i] * vv[j];
        }
    }
  }
  size_t base = (size_t)bh * KSEL + rt * 32;
#pragma unroll
  for (int i = 0; i < 4; ++i) {
    size_t ro = (base + rg * 4 + i) * HDIM;
#pragma unroll
    for (int j = 0; j < 4; ++j) {
      int c = cg * 4 + j;
      q_s[ro + c] = accq[i*4+j];
      k_s[ro + c] = acck[i*4+j];
      v_s[ro + c] = accv[i*4+j];
    }
  }
}

// ---------------- K4: flash attention over sorted selected rows (causal = triangular) ----------------
__global__ __launch_bounds__(256) void k_attn(const float* __restrict__ q_s,
    const float* __restrict__ k_s, const float* __restrict__ v_s,
    float* __restrict__ out_s) {
  __shared__ float kt[64][129];
  __shared__ float vt[64][129];
  __shared__ __align__(16) float qrow[16][128];
  int bh = blockIdx.x;
  int tid = threadIdx.x;
  int wave = tid >> 6, lane = tid & 63;
  int r0 = blockIdx.y * 16;
  size_t bhbase = (size_t)bh * KSEL * HDIM;
  float m[4], l[4], acc0[4], acc1[4], p[4];
#pragma unroll
  for (int rr = 0; rr < 4; ++rr) {
    int r = r0 + wave * 4 + rr;
    size_t ro = bhbase + (size_t)r * HDIM;
    qrow[wave * 4 + rr][lane] = q_s[ro + lane];
    qrow[wave * 4 + rr][lane + 64] = q_s[ro + lane + 64];
    m[rr] = -INFINITY; l[rr] = 0.f; acc0[rr] = 0.f; acc1[rr] = 0.f;
  }
  int ntiles = (r0 + 15) / 64 + 1;
  const float scale = 0.08838834764831845f;  // 1/sqrt(128)
  for (int tt = 0; tt < ntiles; ++tt) {
    int l0 = tt * 64;
    __syncthreads();
    for (int e = tid; e < 64 * HDIM; e += 256) {
      int j = e >> 7, d = e & 127;
      kt[j][d] = k_s[bhbase + (size_t)(l0 + j) * HDIM + d];
      vt[j][d] = v_s[bhbase + (size_t)(l0 + j) * HDIM + d];
    }
    __syncthreads();
    // lane handles key l0+lane for 4 query rows
    float s[4] = {0.f, 0.f, 0.f, 0.f};
#pragma unroll 4
    for (int db = 0; db < 32; ++db) {
      float k0 = kt[lane][db*4+0];
      float k1 = kt[lane][db*4+1];
      float k2 = kt[lane][db*4+2];
      float k3 = kt[lane][db*4+3];
#pragma unroll
      for (int rr = 0; rr < 4; ++rr) {
        float4 qv = *(const float4*)&qrow[wave*4+rr][db*4];
        s[rr] += qv.x*k0 + qv.y*k1 + qv.z*k2 + qv.w*k3;
      }
    }
    int key = l0 + lane;
#pragma unroll
    for (int rr = 0; rr < 4; ++rr) {
      int r = r0 + wave*4 + rr;
      float sv = (key <= r) ? s[rr]*scale : -INFINITY;
      float tm = sv;
#pragma unroll
      for (int off = 32; off; off >>= 1) tm = fmaxf(tm, __shfl_xor(tm, off));
      float newm = fmaxf(m[rr], tm);
      float pv = __expf(sv - newm);
      float corr = __expf(m[rr] - newm);
      float ps = pv;
#pragma unroll
      for (int off = 32; off; off >>= 1) ps += __shfl_xor(ps, off);
      l[rr] = l[rr]*corr + ps;
      acc0[rr] *= corr; acc1[rr] *= corr;
      m[rr] = newm;
      p[rr] = pv;
    }
#pragma unroll 4
    for (int jj = 0; jj < 64; ++jj) {
      float v0 = vt[jj][lane];
      float v1 = vt[jj][lane+64];
#pragma unroll
      for (int rr = 0; rr < 4; ++rr) {
        float pj = __shfl(p[rr], jj);
        acc0[rr] += pj * v0;
        acc1[rr] += pj * v1;
      }
    }
  }
#pragma unroll
  for (int rr = 0; rr < 4; ++rr) {
    int r = r0 + wave*4 + rr;
    size_t ro = bhbase + (size_t)r * HDIM;
    float inv = 1.f / l[rr];
    out_s[ro + lane] = acc0[rr]*inv;
    out_s[ro + lane+64] = acc1[rr]*inv;
  }
}

// ---------------- K5: out projection + scatter-add ----------------
__global__ __launch_bounds__(256) void k_oproj(const float* __restrict__ out_s,
    const float* __restrict__ wo, const int* __restrict__ idx,
    float* __restrict__ out) {
  __shared__ __align__(16) float aT[32][36];
  __shared__ __align__(16) float wT[32][132];
  __shared__ int tIdx[32];
  int bh = blockIdx.x, rt = blockIdx.y, ct = blockIdx.z;
  int b = bh >> 4, h = bh & 15;
  int tid = threadIdx.x;
  if (tid < 32) tIdx[tid] = idx[bh*KSEL + rt*32 + tid];
  int rg = tid & 7, cg = tid >> 3;
  float acc[16];
#pragma unroll
  for (int i = 0; i < 16; ++i) acc[i] = 0.f;
  for (int d0 = 0; d0 < HDIM; d0 += 32) {
    __syncthreads();
    int dd = tid & 31;
    for (int rr = tid >> 5; rr < 32; rr += 8)
      aT[dd][rr] = out_s[((size_t)bh*KSEL + rt*32 + rr)*HDIM + d0 + dd];
    for (int cc = tid >> 5; cc < 128; cc += 8)
      wT[dd][cc] = wo[((size_t)(ct*128 + cc))*DD + h*HDIM + d0 + dd];
    __syncthreads();
#pragma unroll 8
    for (int k2 = 0; k2 < 32; ++k2) {
      float4 a4 = *(const float4*)&aT[k2][rg*4];
      float4 w4 = *(const float4*)&wT[k2][cg*4];
      float av[4] = {a4.x,a4.y,a4.z,a4.w};
      float wv2[4] = {w4.x,w4.y,w4.z,w4.w};
#pragma unroll
      for (int i = 0; i < 4; ++i)
#pragma unroll
        for (int j = 0; j < 4; ++j)
          acc[i*4+j] += av[i]*wv2[j];
    }
  }
#pragma unroll
  for (int i = 0; i < 4; ++i) {
    int t = tIdx[rg*4+i];
    size_t ro = ((size_t)(b*TT + t))*DD + (size_t)ct*128;
#pragma unroll
    for (int j = 0; j < 4; ++j)
      atomicAdd(&out[ro + cg*4 + j], acc[i*4+j]);
  }
}

extern "C" void kernel_launch(void* const* d_in, const int* in_sizes, int n_in,
                              void* d_out, int out_size, void* d_ws, size_t ws_size,
                              hipStream_t stream) {
  (void)in_sizes; (void)n_in; (void)out_size; (void)ws_size;
  const float* x  = (const float*)d_in[0];
  const float* wq = (const float*)d_in[1];
  const float* wk = (const float*)d_in[2];
  const float* wv = (const float*)d_in[3];
  const float* wo = (const float*)d_in[4];
  const float* wr = (const float*)d_in[5];
  float* out = (float*)d_out;

  // workspace layout (≈65 MB)
  float* scores = (float*)d_ws;                                  // B*H*T
  int*   idx    = (int*)(scores + (size_t)BB * HH * TT);         // B*H*K
  float* q_s    = (float*)(idx + NBH * KSEL);
  float* k_s    = q_s + (size_t)NBH * KSEL * HDIM;
  float* v_s    = k_s + (size_t)NBH * KSEL * HDIM;
  float* out_s  = v_s + (size_t)NBH * KSEL * HDIM;

  hipMemsetAsync(d_out, 0, (size_t)BB * TT * DD * sizeof(float), stream);
  k_router<<<BB * TT / 4, 256, 0, stream>>>(x, wr, scores);
  k_topk<<<NBH, 512, 0, stream>>>(scores, idx);
  k_qkv<<<dim3(NBH, KSEL / 32), 256, 0, stream>>>(x, wq, wk, wv, idx, q_s, k_s, v_s);
  k_attn<<<dim3(NBH, KSEL / 16), 256, 0, stream>>>(q_s, k_s, v_s, out_s);
  k_oproj<<<dim3(NBH, KSEL / 32, DD / 128), 256, 0, stream>>>(out_s, wo, idx, out);
}

// Round 2
// 871.555 us; speedup vs baseline: 3.4268x; 3.4268x over previous
//
#include <hip/hip_runtime.h>
#include <math.h>

#define BB 4
#define TT 4096
#define DD 2048
#define HH 16
#define HDIM 128
#define KSEL 512
#define NBH (BB*HH)

using short8  = __attribute__((ext_vector_type(8))) short;
using short4v = __attribute__((ext_vector_type(4))) short;
using f32x4   = __attribute__((ext_vector_type(4))) float;

__device__ __forceinline__ short f2bf(float f) {
  unsigned u = __float_as_uint(f);
  u += 0x7fffu + ((u >> 16) & 1u);   // round-nearest-even
  return (short)(u >> 16);
}
__device__ __forceinline__ float bf2f(short s) {
  return __uint_as_float(((unsigned)(unsigned short)s) << 16);
}

// ---------------- K1: router scores [B,H,T] (f32 — must match ref top-k set) ----------------
__global__ __launch_bounds__(256) void k_router(const float* __restrict__ x,
                                                const float* __restrict__ wr,
                                                float* __restrict__ scores) {
  int wave = threadIdx.x >> 6, lane = threadIdx.x & 63;
  int row = blockIdx.x * 4 + wave;          // b*T + t
  int b = row >> 12, t = row & (TT - 1);
  const float* xr = x + (size_t)row * DD;
  float xi[32];
#pragma unroll
  for (int i = 0; i < 32; ++i) xi[i] = xr[lane + i * 64];
  for (int h = 0; h < HH; ++h) {
    const float* w = wr + (size_t)h * DD;
    float acc = 0.f;
#pragma unroll
    for (int i = 0; i < 32; ++i) acc += xi[i] * w[lane + i * 64];
#pragma unroll
    for (int off = 32; off; off >>= 1) acc += __shfl_xor(acc, off);
    if (lane == 0) scores[((size_t)(b * HH + h)) * TT + t] = acc;
  }
}

// ---------------- K2: per-(b,h) top-512, output ascending by position ----------------
__global__ __launch_bounds__(512) void k_topk(const float* __restrict__ scores,
                                              int* __restrict__ idx) {
  __shared__ unsigned long long keys[TT];
  __shared__ unsigned tsel[KSEL];
  int bh = blockIdx.x, tid = threadIdx.x;
  const float* sc = scores + (size_t)bh * TT;
  for (int i = tid; i < TT; i += 512) {
    unsigned u = __float_as_uint(sc[i]);
    u = (u & 0x80000000u) ? ~u : (u | 0x80000000u);  // monotone map
    keys[i] = ((unsigned long long)u << 32) | (unsigned)(~i); // tie: lower i wins
  }
  __syncthreads();
  for (int k = 2; k <= TT; k <<= 1)
    for (int j = k >> 1; j > 0; j >>= 1) {
      for (int i = tid; i < TT; i += 512) {
        int ixj = i ^ j;
        if (ixj > i) {
          unsigned long long a = keys[i], c = keys[ixj];
          bool asc = ((i & k) == 0);
          if (asc ? (a > c) : (a < c)) { keys[i] = c; keys[ixj] = a; }
        }
      }
      __syncthreads();
    }
  if (tid < KSEL) tsel[tid] = ~((unsigned)keys[TT - KSEL + tid]);
  __syncthreads();
  for (int k = 2; k <= KSEL; k <<= 1)
    for (int j = k >> 1; j > 0; j >>= 1) {
      int i = tid, ixj = tid ^ j;
      if (ixj > i) {
        unsigned a = tsel[i], c = tsel[ixj];
        bool asc = ((i & k) == 0);
        if (asc ? (a > c) : (a < c)) { tsel[i] = c; tsel[ixj] = a; }
      }
      __syncthreads();
    }
  if (tid < KSEL) idx[bh * KSEL + tid] = (int)tsel[tid];
}

// ---------------- K3: gathered QKV projections via bf16 MFMA ----------------
// C[128x128] = A_gathered[128x2048] * W_head[128x2048]^T, both K-major.
// Reg-staged global->cvt->LDS with XOR swizzle (chunk ^= row&7) => conflict-free ds_read_b128.
__global__ __launch_bounds__(256) void k_qkv_mfma(
    const float* __restrict__ x, const float* __restrict__ wq,
    const float* __restrict__ wk, const float* __restrict__ wv,
    const int* __restrict__ idx,
    short* __restrict__ q_s, short* __restrict__ k_s, short* __restrict__ v_s) {
  __shared__ __align__(16) short As[128 * 64];
  __shared__ __align__(16) short Bs[128 * 64];
  __shared__ int tIdx[128];
  const int bh = blockIdx.x, rt = blockIdx.y, which = blockIdx.z;
  const int b = bh >> 4, h = bh & 15;
  const float* __restrict__ w = (which == 0) ? wq : (which == 1) ? wk : wv;
  short* __restrict__ dst = (which == 0) ? q_s : (which == 1) ? k_s : v_s;
  const int tid = threadIdx.x;
  if (tid < 128) tIdx[tid] = idx[bh * KSEL + rt * 128 + tid];
  __syncthreads();
  const int lane = tid & 63, wid = tid >> 6;
  const int wr = wid >> 1, wc = wid & 1;       // 2x2 wave grid, 64x64 each
  const int srow = tid >> 1, khalf = tid & 1;  // staging: 2 threads/row, 32 k each
  const int rm = srow & 7;
  const float* aRow = x + ((size_t)b * TT + tIdx[srow]) * DD + khalf * 32;
  const float* bRow = w + ((size_t)(h * HDIM + srow)) * DD + khalf * 32;
  f32x4 acc[4][4];
#pragma unroll
  for (int m = 0; m < 4; ++m)
#pragma unroll
    for (int n = 0; n < 4; ++n) acc[m][n] = (f32x4){0.f, 0.f, 0.f, 0.f};
  const int r15 = lane & 15, g = lane >> 4;
  for (int k0 = 0; k0 < DD; k0 += 64) {
    __syncthreads();
    {
      const float4* ap = (const float4*)(aRow + k0);
      const float4* bp = (const float4*)(bRow + k0);
      float4 av[8], bv[8];
#pragma unroll
      for (int i = 0; i < 8; ++i) { av[i] = ap[i]; bv[i] = bp[i]; }
#pragma unroll
      for (int c = 0; c < 4; ++c) {
        int chunk = (khalf * 4 + c) ^ rm;
        float4 a0 = av[2 * c], a1 = av[2 * c + 1];
        float4 b0 = bv[2 * c], b1 = bv[2 * c + 1];
        short8 pa, pb;
        pa[0] = f2bf(a0.x); pa[1] = f2bf(a0.y); pa[2] = f2bf(a0.z); pa[3] = f2bf(a0.w);
        pa[4] = f2bf(a1.x); pa[5] = f2bf(a1.y); pa[6] = f2bf(a1.z); pa[7] = f2bf(a1.w);
        pb[0] = f2bf(b0.x); pb[1] = f2bf(b0.y); pb[2] = f2bf(b0.z); pb[3] = f2bf(b0.w);
        pb[4] = f2bf(b1.x); pb[5] = f2bf(b1.y); pb[6] = f2bf(b1.z); pb[7] = f2bf(b1.w);
        *(short8*)&As[srow * 64 + chunk * 8] = pa;
        *(short8*)&Bs[srow * 64 + chunk * 8] = pb;
      }
    }
    __syncthreads();
#pragma unroll
    for (int ks = 0; ks < 2; ++ks) {
      short8 af[4], bfr[4];
#pragma unroll
      for (int m = 0; m < 4; ++m) {
        int row = wr * 64 + m * 16 + r15;
        int chunk = (ks * 4 + g) ^ (row & 7);
        af[m] = *(const short8*)&As[row * 64 + chunk * 8];
      }
#pragma unroll
      for (int n = 0; n < 4; ++n) {
        int col = wc * 64 + n * 16 + r15;
        int chunk = (ks * 4 + g) ^ (col & 7);
        bfr[n] = *(const short8*)&Bs[col * 64 + chunk * 8];
      }
#pragma unroll
      for (int m = 0; m < 4; ++m)
#pragma unroll
        for (int n = 0; n < 4; ++n)
          acc[m][n] = __builtin_amdgcn_mfma_f32_16x16x32_bf16(af[m], bfr[n], acc[m][n], 0, 0, 0);
    }
  }
  const size_t base = (size_t)bh * KSEL + rt * 128;
#pragma unroll
  for (int m = 0; m < 4; ++m) {
    int row0 = wr * 64 + m * 16 + g * 4;   // C/D: col=lane&15, row=(lane>>4)*4+reg
#pragma unroll
    for (int n = 0; n < 4; ++n) {
      int col = wc * 64 + n * 16 + r15;
#pragma unroll
      for (int r = 0; r < 4; ++r)
        dst[(base + row0 + r) * HDIM + col] = f2bf(acc[m][n][r]);
    }
  }
}

// ---------------- K4: flash attention over sorted selected rows (bf16 in/out, f32 compute) ----------------
__global__ __launch_bounds__(256) void k_attn(const short* __restrict__ q_s,
    const short* __restrict__ k_s, const short* __restrict__ v_s,
    short* __restrict__ out_s) {
  __shared__ float kt[64][129];
  __shared__ float vt[64][129];
  __shared__ __align__(16) float qrow[16][128];
  int bh = blockIdx.x;
  int tid = threadIdx.x;
  int wave = tid >> 6, lane = tid & 63;
  int r0 = blockIdx.y * 16;
  size_t bhbase = (size_t)bh * KSEL * HDIM;
  float m[4], l[4], acc0[4], acc1[4], p[4];
#pragma unroll
  for (int rr = 0; rr < 4; ++rr) {
    int r = r0 + wave * 4 + rr;
    size_t ro = bhbase + (size_t)r * HDIM;
    qrow[wave * 4 + rr][lane]      = bf2f(q_s[ro + lane]);
    qrow[wave * 4 + rr][lane + 64] = bf2f(q_s[ro + lane + 64]);
    m[rr] = -INFINITY; l[rr] = 0.f; acc0[rr] = 0.f; acc1[rr] = 0.f;
  }
  int ntiles = (r0 + 15) / 64 + 1;
  const float scale = 0.08838834764831845f;  // 1/sqrt(128)
  for (int tt = 0; tt < ntiles; ++tt) {
    int l0 = tt * 64;
    __syncthreads();
    for (int e = tid; e < 64 * 32; e += 256) {
      int j = e >> 5, d4 = (e & 31) << 2;
      size_t off = bhbase + (size_t)(l0 + j) * HDIM + d4;
      short4v kk = *(const short4v*)&k_s[off];
      short4v vv = *(const short4v*)&v_s[off];
      kt[j][d4 + 0] = bf2f(kk[0]); kt[j][d4 + 1] = bf2f(kk[1]);
      kt[j][d4 + 2] = bf2f(kk[2]); kt[j][d4 + 3] = bf2f(kk[3]);
      vt[j][d4 + 0] = bf2f(vv[0]); vt[j][d4 + 1] = bf2f(vv[1]);
      vt[j][d4 + 2] = bf2f(vv[2]); vt[j][d4 + 3] = bf2f(vv[3]);
    }
    __syncthreads();
    float s[4] = {0.f, 0.f, 0.f, 0.f};
#pragma unroll 4
    for (int db = 0; db < 32; ++db) {
      float k0v = kt[lane][db*4+0];
      float k1v = kt[lane][db*4+1];
      float k2v = kt[lane][db*4+2];
      float k3v = kt[lane][db*4+3];
#pragma unroll
      for (int rr = 0; rr < 4; ++rr) {
        float4 qv = *(const float4*)&qrow[wave*4+rr][db*4];
        s[rr] += qv.x*k0v + qv.y*k1v + qv.z*k2v + qv.w*k3v;
      }
    }
    int key = l0 + lane;
#pragma unroll
    for (int rr = 0; rr < 4; ++rr) {
      int r = r0 + wave*4 + rr;
      float sv = (key <= r) ? s[rr]*scale : -INFINITY;
      float tm = sv;
#pragma unroll
      for (int off = 32; off; off >>= 1) tm = fmaxf(tm, __shfl_xor(tm, off));
      float newm = fmaxf(m[rr], tm);
      float pv = __expf(sv - newm);
      float corr = __expf(m[rr] - newm);
      float ps = pv;
#pragma unroll
      for (int off = 32; off; off >>= 1) ps += __shfl_xor(ps, off);
      l[rr] = l[rr]*corr + ps;
      acc0[rr] *= corr; acc1[rr] *= corr;
      m[rr] = newm;
      p[rr] = pv;
    }
#pragma unroll 4
    for (int jj = 0; jj < 64; ++jj) {
      float v0 = vt[jj][lane];
      float v1 = vt[jj][lane+64];
#pragma unroll
      for (int rr = 0; rr < 4; ++rr) {
        float pj = __shfl(p[rr], jj);
        acc0[rr] += pj * v0;
        acc1[rr] += pj * v1;
      }
    }
  }
#pragma unroll
  for (int rr = 0; rr < 4; ++rr) {
    int r = r0 + wave*4 + rr;
    size_t ro = bhbase + (size_t)r * HDIM;
    float inv = 1.f / l[rr];
    out_s[ro + lane]      = f2bf(acc0[rr]*inv);
    out_s[ro + lane + 64] = f2bf(acc1[rr]*inv);
  }
}

// ---------------- K5: out projection via bf16 MFMA + atomic scatter ----------------
// C[128 rows x 128 ch] = out_s[128x128] * wo_slice[128x128]^T, K=128 (2 steps of 64).
__global__ __launch_bounds__(256) void k_oproj_mfma(
    const short* __restrict__ out_s, const float* __restrict__ wo,
    const int* __restrict__ idx, float* __restrict__ out) {
  __shared__ __align__(16) short As[128 * 64];
  __shared__ __align__(16) short Bs[128 * 64];
  __shared__ int tIdx[128];
  const int bh = blockIdx.x, rt = blockIdx.y, ct = blockIdx.z;
  const int b = bh >> 4, h = bh & 15;
  const int tid = threadIdx.x;
  if (tid < 128) tIdx[tid] = idx[bh * KSEL + rt * 128 + tid];
  __syncthreads();
  const int lane = tid & 63, wid = tid >> 6;
  const int wr = wid >> 1, wc = wid & 1;
  const int srow = tid >> 1, khalf = tid & 1;
  const int rm = srow & 7;
  const short* aRow = out_s + ((size_t)bh * KSEL + rt * 128 + srow) * HDIM + khalf * 32;
  const float* bRow = wo + ((size_t)(ct * 128 + srow)) * DD + h * HDIM + khalf * 32;
  f32x4 acc[4][4];
#pragma unroll
  for (int m = 0; m < 4; ++m)
#pragma unroll
    for (int n = 0; n < 4; ++n) acc[m][n] = (f32x4){0.f, 0.f, 0.f, 0.f};
  const int r15 = lane & 15, g = lane >> 4;
#pragma unroll
  for (int k0 = 0; k0 < HDIM; k0 += 64) {
    __syncthreads();
    {
      const short8* ap = (const short8*)(aRow + k0);
      const float4* bp = (const float4*)(bRow + k0);
      short8 av[4]; float4 bv[8];
#pragma unroll
      for (int i = 0; i < 4; ++i) av[i] = ap[i];
#pragma unroll
      for (int i = 0; i < 8; ++i) bv[i] = bp[i];
#pragma unroll
      for (int c = 0; c < 4; ++c) {
        int chunk = (khalf * 4 + c) ^ rm;
        float4 b0 = bv[2 * c], b1 = bv[2 * c + 1];
        short8 pb;
        pb[0] = f2bf(b0.x); pb[1] = f2bf(b0.y); pb[2] = f2bf(b0.z); pb[3] = f2bf(b0.w);
        pb[4] = f2bf(b1.x); pb[5] = f2bf(b1.y); pb[6] = f2bf(b1.z); pb[7] = f2bf(b1.w);
        *(short8*)&As[srow * 64 + chunk * 8] = av[c];
        *(short8*)&Bs[srow * 64 + chunk * 8] = pb;
      }
    }
    __syncthreads();
#pragma unroll
    for (int ks = 0; ks < 2; ++ks) {
      short8 af[4], bfr[4];
#pragma unroll
      for (int m = 0; m < 4; ++m) {
        int row = wr * 64 + m * 16 + r15;
        int chunk = (ks * 4 + g) ^ (row & 7);
        af[m] = *(const short8*)&As[row * 64 + chunk * 8];
      }
#pragma unroll
      for (int n = 0; n < 4; ++n) {
        int col = wc * 64 + n * 16 + r15;
        int chunk = (ks * 4 + g) ^ (col & 7);
        bfr[n] = *(const short8*)&Bs[col * 64 + chunk * 8];
      }
#pragma unroll
      for (int m = 0; m < 4; ++m)
#pragma unroll
        for (int n = 0; n < 4; ++n)
          acc[m][n] = __builtin_amdgcn_mfma_f32_16x16x32_bf16(af[m], bfr[n], acc[m][n], 0, 0, 0);
    }
  }
#pragma unroll
  for (int m = 0; m < 4; ++m) {
#pragma unroll
    for (int r = 0; r < 4; ++r) {
      int row = wr * 64 + m * 16 + g * 4 + r;
      int t = tIdx[row];
      float* orow = out + ((size_t)b * TT + t) * DD + ct * 128;
#pragma unroll
      for (int n = 0; n < 4; ++n) {
        int col = wc * 64 + n * 16 + r15;
        atomicAdd(&orow[col], acc[m][n][r]);
      }
    }
  }
}

extern "C" void kernel_launch(void* const* d_in, const int* in_sizes, int n_in,
                              void* d_out, int out_size, void* d_ws, size_t ws_size,
                              hipStream_t stream) {
  (void)in_sizes; (void)n_in; (void)out_size; (void)ws_size;
  const float* x  = (const float*)d_in[0];
  const float* wq = (const float*)d_in[1];
  const float* wk = (const float*)d_in[2];
  const float* wv = (const float*)d_in[3];
  const float* wo = (const float*)d_in[4];
  const float* wr = (const float*)d_in[5];
  float* out = (float*)d_out;

  // workspace layout (~35 MB)
  float* scores = (float*)d_ws;                                  // B*H*T f32
  int*   idx    = (int*)(scores + (size_t)BB * HH * TT);         // B*H*K
  short* q_s    = (short*)(idx + NBH * KSEL);                    // bf16 bits
  short* k_s    = q_s + (size_t)NBH * KSEL * HDIM;
  short* v_s    = k_s + (size_t)NBH * KSEL * HDIM;
  short* out_s  = v_s + (size_t)NBH * KSEL * HDIM;

  hipMemsetAsync(d_out, 0, (size_t)BB * TT * DD * sizeof(float), stream);
  k_router<<<BB * TT / 4, 256, 0, stream>>>(x, wr, scores);
  k_topk<<<NBH, 512, 0, stream>>>(scores, idx);
  k_qkv_mfma<<<dim3(NBH, KSEL / 128, 3), 256, 0, stream>>>(x, wq, wk, wv, idx, q_s, k_s, v_s);
  k_attn<<<dim3(NBH, KSEL / 16), 256, 0, stream>>>(q_s, k_s, v_s, out_s);
  k_oproj_mfma<<<dim3(NBH, KSEL / 128, DD / 128), 256, 0, stream>>>(out_s, wo, idx, out);
}

// Round 3
// 665.967 us; speedup vs baseline: 4.4846x; 1.3087x over previous
//
#include <hip/hip_runtime.h>
#include <math.h>

#define BB 4
#define TT 4096
#define DD 2048
#define HH 16
#define HDIM 128
#define KSEL 512
#define NBH (BB*HH)

using short8  = __attribute__((ext_vector_type(8))) short;
using short4v = __attribute__((ext_vector_type(4))) short;
using f32x4   = __attribute__((ext_vector_type(4))) float;

__device__ __forceinline__ short f2bf(float f) {
  unsigned u = __float_as_uint(f);
  u += 0x7fffu + ((u >> 16) & 1u);   // round-nearest-even
  return (short)(u >> 16);
}
__device__ __forceinline__ float bf2f(short s) {
  return __uint_as_float(((unsigned)(unsigned short)s) << 16);
}

// ---------------- K1: router scores [B,H,T] (f32 — must match ref top-k set) ----------------
__global__ __launch_bounds__(256) void k_router(const float* __restrict__ x,
                                                const float* __restrict__ wr,
                                                float* __restrict__ scores) {
  int wave = threadIdx.x >> 6, lane = threadIdx.x & 63;
  int row = blockIdx.x * 4 + wave;          // b*T + t
  int b = row >> 12, t = row & (TT - 1);
  const float* xr = x + (size_t)row * DD;
  float xi[32];
#pragma unroll
  for (int i = 0; i < 32; ++i) xi[i] = xr[lane + i * 64];
  for (int h = 0; h < HH; ++h) {
    const float* w = wr + (size_t)h * DD;
    float acc = 0.f;
#pragma unroll
    for (int i = 0; i < 32; ++i) acc += xi[i] * w[lane + i * 64];
#pragma unroll
    for (int off = 32; off; off >>= 1) acc += __shfl_xor(acc, off);
    if (lane == 0) scores[((size_t)(b * HH + h)) * TT + t] = acc;
  }
}

// ---------------- K2: per-(b,h) top-512, output ascending by position ----------------
__global__ __launch_bounds__(512) void k_topk(const float* __restrict__ scores,
                                              int* __restrict__ idx) {
  __shared__ unsigned long long keys[TT];
  __shared__ unsigned tsel[KSEL];
  int bh = blockIdx.x, tid = threadIdx.x;
  const float* sc = scores + (size_t)bh * TT;
  for (int i = tid; i < TT; i += 512) {
    unsigned u = __float_as_uint(sc[i]);
    u = (u & 0x80000000u) ? ~u : (u | 0x80000000u);  // monotone map
    keys[i] = ((unsigned long long)u << 32) | (unsigned)(~i); // tie: lower i wins
  }
  __syncthreads();
  for (int k = 2; k <= TT; k <<= 1)
    for (int j = k >> 1; j > 0; j >>= 1) {
      for (int i = tid; i < TT; i += 512) {
        int ixj = i ^ j;
        if (ixj > i) {
          unsigned long long a = keys[i], c = keys[ixj];
          bool asc = ((i & k) == 0);
          if (asc ? (a > c) : (a < c)) { keys[i] = c; keys[ixj] = a; }
        }
      }
      __syncthreads();
    }
  if (tid < KSEL) tsel[tid] = ~((unsigned)keys[TT - KSEL + tid]);
  __syncthreads();
  for (int k = 2; k <= KSEL; k <<= 1)
    for (int j = k >> 1; j > 0; j >>= 1) {
      int i = tid, ixj = tid ^ j;
      if (ixj > i) {
        unsigned a = tsel[i], c = tsel[ixj];
        bool asc = ((i & k) == 0);
        if (asc ? (a > c) : (a < c)) { tsel[i] = c; tsel[ixj] = a; }
      }
      __syncthreads();
    }
  if (tid < KSEL) idx[bh * KSEL + tid] = (int)tsel[tid];
}

// ---------------- K3: gathered QKV projections via bf16 MFMA ----------------
__global__ __launch_bounds__(256) void k_qkv_mfma(
    const float* __restrict__ x, const float* __restrict__ wq,
    const float* __restrict__ wk, const float* __restrict__ wv,
    const int* __restrict__ idx,
    short* __restrict__ q_s, short* __restrict__ k_s, short* __restrict__ v_s) {
  __shared__ __align__(16) short As[128 * 64];
  __shared__ __align__(16) short Bs[128 * 64];
  __shared__ int tIdx[128];
  const int bh = blockIdx.x, rt = blockIdx.y, which = blockIdx.z;
  const int b = bh >> 4, h = bh & 15;
  const float* __restrict__ w = (which == 0) ? wq : (which == 1) ? wk : wv;
  short* __restrict__ dst = (which == 0) ? q_s : (which == 1) ? k_s : v_s;
  const int tid = threadIdx.x;
  if (tid < 128) tIdx[tid] = idx[bh * KSEL + rt * 128 + tid];
  __syncthreads();
  const int lane = tid & 63, wid = tid >> 6;
  const int wr = wid >> 1, wc = wid & 1;       // 2x2 wave grid, 64x64 each
  const int srow = tid >> 1, khalf = tid & 1;  // staging: 2 threads/row, 32 k each
  const int rm = srow & 7;
  const float* aRow = x + ((size_t)b * TT + tIdx[srow]) * DD + khalf * 32;
  const float* bRow = w + ((size_t)(h * HDIM + srow)) * DD + khalf * 32;
  f32x4 acc[4][4];
#pragma unroll
  for (int m = 0; m < 4; ++m)
#pragma unroll
    for (int n = 0; n < 4; ++n) acc[m][n] = (f32x4){0.f, 0.f, 0.f, 0.f};
  const int r15 = lane & 15, g = lane >> 4;
  for (int k0 = 0; k0 < DD; k0 += 64) {
    __syncthreads();
    {
      const float4* ap = (const float4*)(aRow + k0);
      const float4* bp = (const float4*)(bRow + k0);
      float4 av[8], bv[8];
#pragma unroll
      for (int i = 0; i < 8; ++i) { av[i] = ap[i]; bv[i] = bp[i]; }
#pragma unroll
      for (int c = 0; c < 4; ++c) {
        int chunk = (khalf * 4 + c) ^ rm;
        float4 a0 = av[2 * c], a1 = av[2 * c + 1];
        float4 b0 = bv[2 * c], b1 = bv[2 * c + 1];
        short8 pa, pb;
        pa[0] = f2bf(a0.x); pa[1] = f2bf(a0.y); pa[2] = f2bf(a0.z); pa[3] = f2bf(a0.w);
        pa[4] = f2bf(a1.x); pa[5] = f2bf(a1.y); pa[6] = f2bf(a1.z); pa[7] = f2bf(a1.w);
        pb[0] = f2bf(b0.x); pb[1] = f2bf(b0.y); pb[2] = f2bf(b0.z); pb[3] = f2bf(b0.w);
        pb[4] = f2bf(b1.x); pb[5] = f2bf(b1.y); pb[6] = f2bf(b1.z); pb[7] = f2bf(b1.w);
        *(short8*)&As[srow * 64 + chunk * 8] = pa;
        *(short8*)&Bs[srow * 64 + chunk * 8] = pb;
      }
    }
    __syncthreads();
#pragma unroll
    for (int ks = 0; ks < 2; ++ks) {
      short8 af[4], bfr[4];
#pragma unroll
      for (int m = 0; m < 4; ++m) {
        int row = wr * 64 + m * 16 + r15;
        int chunk = (ks * 4 + g) ^ (row & 7);
        af[m] = *(const short8*)&As[row * 64 + chunk * 8];
      }
#pragma unroll
      for (int n = 0; n < 4; ++n) {
        int col = wc * 64 + n * 16 + r15;
        int chunk = (ks * 4 + g) ^ (col & 7);
        bfr[n] = *(const short8*)&Bs[col * 64 + chunk * 8];
      }
#pragma unroll
      for (int m = 0; m < 4; ++m)
#pragma unroll
        for (int n = 0; n < 4; ++n)
          acc[m][n] = __builtin_amdgcn_mfma_f32_16x16x32_bf16(af[m], bfr[n], acc[m][n], 0, 0, 0);
    }
  }
  const size_t base = (size_t)bh * KSEL + rt * 128;
#pragma unroll
  for (int m = 0; m < 4; ++m) {
    int row0 = wr * 64 + m * 16 + g * 4;   // C/D: col=lane&15, row=(lane>>4)*4+reg
#pragma unroll
    for (int n = 0; n < 4; ++n) {
      int col = wc * 64 + n * 16 + r15;
#pragma unroll
      for (int r = 0; r < 4; ++r)
        dst[(base + row0 + r) * HDIM + col] = f2bf(acc[m][n][r]);
    }
  }
}

// ---------------- K4: MFMA flash attention over sorted selected rows ----------------
// Block: 4 waves, 64 q-rows (16/wave), key tiles of 64. Causal = triangular (sorted idx).
__global__ __launch_bounds__(256) void k_attn_mfma(const short* __restrict__ q_s,
    const short* __restrict__ k_s, const short* __restrict__ v_s,
    short* __restrict__ out_s) {
  __shared__ __align__(16) short Ks[64 * 128];    // [key][dim], chunk^=(key&7)
  __shared__ __align__(16) short Vt[128 * 64];    // [dim][key], chunk^=(dim&7)
  __shared__ __align__(16) short Pl[4 * 16 * 72]; // per-wave P tile, pad 72
  const int bh = blockIdx.x, qt = blockIdx.y;
  const int tid = threadIdx.x;
  const int w = tid >> 6, lane = tid & 63;
  const int g = lane >> 4, r15 = lane & 15;
  const size_t bhbase = (size_t)bh * KSEL * HDIM;
  const int r0 = qt * 64;
  const float scale = 0.08838834764831845f;  // 1/sqrt(128)

  // Q fragments in registers (A-frag: row=r15, k = ks*32 + g*8 + j)
  short8 qf[4];
  {
    const short* qrow = q_s + bhbase + (size_t)(r0 + w * 16 + r15) * HDIM;
#pragma unroll
    for (int ks = 0; ks < 4; ++ks)
      qf[ks] = *(const short8*)(qrow + ks * 32 + g * 8);
  }
  f32x4 o[8];
#pragma unroll
  for (int n = 0; n < 8; ++n) o[n] = (f32x4){0.f, 0.f, 0.f, 0.f};
  float mrow[4] = {-INFINITY, -INFINITY, -INFINITY, -INFINITY};
  float lrow[4] = {0.f, 0.f, 0.f, 0.f};

  short* myP = &Pl[w * 16 * 72];
  const short* kbase0 = k_s + bhbase + (size_t)lane * HDIM + w * 32;
  const short* vbase0 = v_s + bhbase + (size_t)lane * HDIM + w * 32;

  for (int kt = 0; kt <= qt; ++kt) {
    __syncthreads();
    {
      const short* kb = kbase0 + (size_t)kt * 64 * HDIM;
      const short* vb = vbase0 + (size_t)kt * 64 * HDIM;
#pragma unroll
      for (int i8 = 0; i8 < 4; ++i8) {
        int chunk = w * 4 + i8;
        short8 kv = *(const short8*)(kb + i8 * 8);
        *(short8*)&Ks[lane * 128 + (chunk ^ (lane & 7)) * 8] = kv;
        short8 vv = *(const short8*)(vb + i8 * 8);
        int d0 = w * 32 + i8 * 8;
#pragma unroll
        for (int e = 0; e < 8; ++e) {
          int d = d0 + e;
          Vt[d * 64 + (((lane >> 3) ^ (d & 7)) << 3) + (lane & 7)] = vv[e];
        }
      }
    }
    __syncthreads();

    // S = Q K^T (16 q-rows x 64 keys per wave)
    f32x4 s[4];
#pragma unroll
    for (int n = 0; n < 4; ++n) s[n] = (f32x4){0.f, 0.f, 0.f, 0.f};
#pragma unroll
    for (int ks = 0; ks < 4; ++ks) {
#pragma unroll
      for (int n = 0; n < 4; ++n) {
        int row = n * 16 + r15;
        short8 kf = *(const short8*)&Ks[row * 128 + ((ks * 4 + g) ^ (r15 & 7)) * 8];
        s[n] = __builtin_amdgcn_mfma_f32_16x16x32_bf16(qf[ks], kf, s[n], 0, 0, 0);
      }
    }

    // online softmax in C-layout (lane holds rows g*4+r, cols n*16+r15)
    const bool diag = (kt == qt);
    float sv[4][4];
#pragma unroll
    for (int n = 0; n < 4; ++n) {
      int key = kt * 64 + n * 16 + r15;
#pragma unroll
      for (int r = 0; r < 4; ++r) {
        float xv = s[n][r] * scale;
        int qrow = r0 + w * 16 + g * 4 + r;
        sv[n][r] = (diag && key > qrow) ? -INFINITY : xv;
      }
    }
    float corr[4];
#pragma unroll
    for (int r = 0; r < 4; ++r) {
      float tm = fmaxf(fmaxf(sv[0][r], sv[1][r]), fmaxf(sv[2][r], sv[3][r]));
#pragma unroll
      for (int off = 8; off; off >>= 1) tm = fmaxf(tm, __shfl_xor(tm, off));
      float newm = fmaxf(mrow[r], tm);
      corr[r] = __expf(mrow[r] - newm);
      mrow[r] = newm;
      float ps = 0.f;
#pragma unroll
      for (int n = 0; n < 4; ++n) {
        float pv = __expf(sv[n][r] - newm);
        sv[n][r] = pv;
        ps += pv;
      }
#pragma unroll
      for (int off = 8; off; off >>= 1) ps += __shfl_xor(ps, off);
      lrow[r] = lrow[r] * corr[r] + ps;
    }
    // write P (bf16) to wave-private LDS; rescale O
    f32x4 corrv = {corr[0], corr[1], corr[2], corr[3]};
#pragma unroll
    for (int n = 0; n < 4; ++n)
#pragma unroll
      for (int r = 0; r < 4; ++r)
        myP[(g * 4 + r) * 72 + n * 16 + r15] = f2bf(sv[n][r]);
#pragma unroll
    for (int n = 0; n < 8; ++n) o[n] *= corrv;

    // PV: A = P (rows=q, k=keys), B = Vt rows (dims, k=keys)
    short8 pf[2];
#pragma unroll
    for (int ks = 0; ks < 2; ++ks)
      pf[ks] = *(const short8*)&myP[r15 * 72 + ks * 32 + g * 8];
#pragma unroll
    for (int ks = 0; ks < 2; ++ks)
#pragma unroll
      for (int n2 = 0; n2 < 8; ++n2) {
        int row = n2 * 16 + r15;
        short8 vf = *(const short8*)&Vt[row * 64 + ((ks * 4 + g) ^ (r15 & 7)) * 8];
        o[n2] = __builtin_amdgcn_mfma_f32_16x16x32_bf16(pf[ks], vf, o[n2], 0, 0, 0);
      }
  }

  float inv[4];
#pragma unroll
  for (int r = 0; r < 4; ++r) inv[r] = 1.f / lrow[r];
#pragma unroll
  for (int n2 = 0; n2 < 8; ++n2) {
#pragma unroll
    for (int r = 0; r < 4; ++r) {
      int qrow = r0 + w * 16 + g * 4 + r;
      out_s[bhbase + (size_t)qrow * HDIM + n2 * 16 + r15] = f2bf(o[n2][r] * inv[r]);
    }
  }
}

// ---------------- K5: out projection via bf16 MFMA + atomic scatter ----------------
__global__ __launch_bounds__(256) void k_oproj_mfma(
    const short* __restrict__ out_s, const float* __restrict__ wo,
    const int* __restrict__ idx, float* __restrict__ out) {
  __shared__ __align__(16) short As[128 * 64];
  __shared__ __align__(16) short Bs[128 * 64];
  __shared__ int tIdx[128];
  const int bh = blockIdx.x, rt = blockIdx.y, ct = blockIdx.z;
  const int b = bh >> 4, h = bh & 15;
  const int tid = threadIdx.x;
  if (tid < 128) tIdx[tid] = idx[bh * KSEL + rt * 128 + tid];
  __syncthreads();
  const int lane = tid & 63, wid = tid >> 6;
  const int wr = wid >> 1, wc = wid & 1;
  const int srow = tid >> 1, khalf = tid & 1;
  const int rm = srow & 7;
  const short* aRow = out_s + ((size_t)bh * KSEL + rt * 128 + srow) * HDIM + khalf * 32;
  const float* bRow = wo + ((size_t)(ct * 128 + srow)) * DD + h * HDIM + khalf * 32;
  f32x4 acc[4][4];
#pragma unroll
  for (int m = 0; m < 4; ++m)
#pragma unroll
    for (int n = 0; n < 4; ++n) acc[m][n] = (f32x4){0.f, 0.f, 0.f, 0.f};
  const int r15 = lane & 15, g = lane >> 4;
#pragma unroll
  for (int k0 = 0; k0 < HDIM; k0 += 64) {
    __syncthreads();
    {
      const short8* ap = (const short8*)(aRow + k0);
      const float4* bp = (const float4*)(bRow + k0);
      short8 av[4]; float4 bv[8];
#pragma unroll
      for (int i = 0; i < 4; ++i) av[i] = ap[i];
#pragma unroll
      for (int i = 0; i < 8; ++i) bv[i] = bp[i];
#pragma unroll
      for (int c = 0; c < 4; ++c) {
        int chunk = (khalf * 4 + c) ^ rm;
        float4 b0 = bv[2 * c], b1 = bv[2 * c + 1];
        short8 pb;
        pb[0] = f2bf(b0.x); pb[1] = f2bf(b0.y); pb[2] = f2bf(b0.z); pb[3] = f2bf(b0.w);
        pb[4] = f2bf(b1.x); pb[5] = f2bf(b1.y); pb[6] = f2bf(b1.z); pb[7] = f2bf(b1.w);
        *(short8*)&As[srow * 64 + chunk * 8] = av[c];
        *(short8*)&Bs[srow * 64 + chunk * 8] = pb;
      }
    }
    __syncthreads();
#pragma unroll
    for (int ks = 0; ks < 2; ++ks) {
      short8 af[4], bfr[4];
#pragma unroll
      for (int m = 0; m < 4; ++m) {
        int row = wr * 64 + m * 16 + r15;
        int chunk = (ks * 4 + g) ^ (row & 7);
        af[m] = *(const short8*)&As[row * 64 + chunk * 8];
      }
#pragma unroll
      for (int n = 0; n < 4; ++n) {
        int col = wc * 64 + n * 16 + r15;
        int chunk = (ks * 4 + g) ^ (col & 7);
        bfr[n] = *(const short8*)&Bs[col * 64 + chunk * 8];
      }
#pragma unroll
      for (int m = 0; m < 4; ++m)
#pragma unroll
        for (int n = 0; n < 4; ++n)
          acc[m][n] = __builtin_amdgcn_mfma_f32_16x16x32_bf16(af[m], bfr[n], acc[m][n], 0, 0, 0);
    }
  }
#pragma unroll
  for (int m = 0; m < 4; ++m) {
#pragma unroll
    for (int r = 0; r < 4; ++r) {
      int row = wr * 64 + m * 16 + g * 4 + r;
      int t = tIdx[row];
      float* orow = out + ((size_t)b * TT + t) * DD + ct * 128;
#pragma unroll
      for (int n = 0; n < 4; ++n) {
        int col = wc * 64 + n * 16 + r15;
        atomicAdd(&orow[col], acc[m][n][r]);
      }
    }
  }
}

extern "C" void kernel_launch(void* const* d_in, const int* in_sizes, int n_in,
                              void* d_out, int out_size, void* d_ws, size_t ws_size,
                              hipStream_t stream) {
  (void)in_sizes; (void)n_in; (void)out_size; (void)ws_size;
  const float* x  = (const float*)d_in[0];
  const float* wq = (const float*)d_in[1];
  const float* wk = (const float*)d_in[2];
  const float* wv = (const float*)d_in[3];
  const float* wo = (const float*)d_in[4];
  const float* wr = (const float*)d_in[5];
  float* out = (float*)d_out;

  float* scores = (float*)d_ws;                                  // B*H*T f32
  int*   idx    = (int*)(scores + (size_t)BB * HH * TT);         // B*H*K
  short* q_s    = (short*)(idx + NBH * KSEL);                    // bf16 bits
  short* k_s    = q_s + (size_t)NBH * KSEL * HDIM;
  short* v_s    = k_s + (size_t)NBH * KSEL * HDIM;
  short* out_s  = v_s + (size_t)NBH * KSEL * HDIM;

  hipMemsetAsync(d_out, 0, (size_t)BB * TT * DD * sizeof(float), stream);
  k_router<<<BB * TT / 4, 256, 0, stream>>>(x, wr, scores);
  k_topk<<<NBH, 512, 0, stream>>>(scores, idx);
  k_qkv_mfma<<<dim3(NBH, KSEL / 128, 3), 256, 0, stream>>>(x, wq, wk, wv, idx, q_s, k_s, v_s);
  k_attn_mfma<<<dim3(NBH, KSEL / 64), 256, 0, stream>>>(q_s, k_s, v_s, out_s);
  k_oproj_mfma<<<dim3(NBH, KSEL / 128, DD / 128), 256, 0, stream>>>(out_s, wo, idx, out);
}

// Round 4
// 574.171 us; speedup vs baseline: 5.2016x; 1.1599x over previous
//
#include <hip/hip_runtime.h>
#include <math.h>

#define BB 4
#define TT 4096
#define DD 2048
#define HH 16
#define HDIM 128
#define KSEL 512
#define NBH (BB*HH)

using short8  = __attribute__((ext_vector_type(8))) short;
using short4v = __attribute__((ext_vector_type(4))) short;
using f32x4   = __attribute__((ext_vector_type(4))) float;

__device__ __forceinline__ short f2bf(float f) {
  unsigned u = __float_as_uint(f);
  u += 0x7fffu + ((u >> 16) & 1u);   // round-nearest-even
  return (short)(u >> 16);
}
__device__ __forceinline__ float bf2f(short s) {
  return __uint_as_float(((unsigned)(unsigned short)s) << 16);
}

// ---------------- K1: router scores [B,H,T] (f32 — must match ref top-k set) ----------------
__global__ __launch_bounds__(256) void k_router(const float* __restrict__ x,
                                                const float* __restrict__ wr,
                                                float* __restrict__ scores) {
  int wave = threadIdx.x >> 6, lane = threadIdx.x & 63;
  int row = blockIdx.x * 4 + wave;          // b*T + t
  int b = row >> 12, t = row & (TT - 1);
  const float* xr = x + (size_t)row * DD;
  float xi[32];
#pragma unroll
  for (int i = 0; i < 32; ++i) xi[i] = xr[lane + i * 64];
  for (int h = 0; h < HH; ++h) {
    const float* w = wr + (size_t)h * DD;
    float acc = 0.f;
#pragma unroll
    for (int i = 0; i < 32; ++i) acc += xi[i] * w[lane + i * 64];
#pragma unroll
    for (int off = 32; off; off >>= 1) acc += __shfl_xor(acc, off);
    if (lane == 0) scores[((size_t)(b * HH + h)) * TT + t] = acc;
  }
}

// ---------------- K2: per-(b,h) top-512, output ascending by position ----------------
__global__ __launch_bounds__(512) void k_topk(const float* __restrict__ scores,
                                              int* __restrict__ idx) {
  __shared__ unsigned long long keys[TT];
  __shared__ unsigned tsel[KSEL];
  int bh = blockIdx.x, tid = threadIdx.x;
  const float* sc = scores + (size_t)bh * TT;
  for (int i = tid; i < TT; i += 512) {
    unsigned u = __float_as_uint(sc[i]);
    u = (u & 0x80000000u) ? ~u : (u | 0x80000000u);  // monotone map
    keys[i] = ((unsigned long long)u << 32) | (unsigned)(~i); // tie: lower i wins
  }
  __syncthreads();
  for (int k = 2; k <= TT; k <<= 1)
    for (int j = k >> 1; j > 0; j >>= 1) {
      for (int i = tid; i < TT; i += 512) {
        int ixj = i ^ j;
        if (ixj > i) {
          unsigned long long a = keys[i], c = keys[ixj];
          bool asc = ((i & k) == 0);
          if (asc ? (a > c) : (a < c)) { keys[i] = c; keys[ixj] = a; }
        }
      }
      __syncthreads();
    }
  if (tid < KSEL) tsel[tid] = ~((unsigned)keys[TT - KSEL + tid]);
  __syncthreads();
  for (int k = 2; k <= KSEL; k <<= 1)
    for (int j = k >> 1; j > 0; j >>= 1) {
      int i = tid, ixj = tid ^ j;
      if (ixj > i) {
        unsigned a = tsel[i], c = tsel[ixj];
        bool asc = ((i & k) == 0);
        if (asc ? (a > c) : (a < c)) { tsel[i] = c; tsel[ixj] = a; }
      }
      __syncthreads();
    }
  if (tid < KSEL) idx[bh * KSEL + tid] = (int)tsel[tid];
}

// ---------------- K3: gathered QKV projections via bf16 MFMA ----------------
__global__ __launch_bounds__(256) void k_qkv_mfma(
    const float* __restrict__ x, const float* __restrict__ wq,
    const float* __restrict__ wk, const float* __restrict__ wv,
    const int* __restrict__ idx,
    short* __restrict__ q_s, short* __restrict__ k_s, short* __restrict__ v_s) {
  __shared__ __align__(16) short As[128 * 64];
  __shared__ __align__(16) short Bs[128 * 64];
  __shared__ int tIdx[128];
  const int bh = blockIdx.x, rt = blockIdx.y, which = blockIdx.z;
  const int b = bh >> 4, h = bh & 15;
  const float* __restrict__ w = (which == 0) ? wq : (which == 1) ? wk : wv;
  short* __restrict__ dst = (which == 0) ? q_s : (which == 1) ? k_s : v_s;
  const int tid = threadIdx.x;
  if (tid < 128) tIdx[tid] = idx[bh * KSEL + rt * 128 + tid];
  __syncthreads();
  const int lane = tid & 63, wid = tid >> 6;
  const int wr = wid >> 1, wc = wid & 1;       // 2x2 wave grid, 64x64 each
  const int srow = tid >> 1, khalf = tid & 1;  // staging: 2 threads/row, 32 k each
  const int rm = srow & 7;
  const float* aRow = x + ((size_t)b * TT + tIdx[srow]) * DD + khalf * 32;
  const float* bRow = w + ((size_t)(h * HDIM + srow)) * DD + khalf * 32;
  f32x4 acc[4][4];
#pragma unroll
  for (int m = 0; m < 4; ++m)
#pragma unroll
    for (int n = 0; n < 4; ++n) acc[m][n] = (f32x4){0.f, 0.f, 0.f, 0.f};
  const int r15 = lane & 15, g = lane >> 4;
  for (int k0 = 0; k0 < DD; k0 += 64) {
    __syncthreads();
    {
      const float4* ap = (const float4*)(aRow + k0);
      const float4* bp = (const float4*)(bRow + k0);
      float4 av[8], bv[8];
#pragma unroll
      for (int i = 0; i < 8; ++i) { av[i] = ap[i]; bv[i] = bp[i]; }
#pragma unroll
      for (int c = 0; c < 4; ++c) {
        int chunk = (khalf * 4 + c) ^ rm;
        float4 a0 = av[2 * c], a1 = av[2 * c + 1];
        float4 b0 = bv[2 * c], b1 = bv[2 * c + 1];
        short8 pa, pb;
        pa[0] = f2bf(a0.x); pa[1] = f2bf(a0.y); pa[2] = f2bf(a0.z); pa[3] = f2bf(a0.w);
        pa[4] = f2bf(a1.x); pa[5] = f2bf(a1.y); pa[6] = f2bf(a1.z); pa[7] = f2bf(a1.w);
        pb[0] = f2bf(b0.x); pb[1] = f2bf(b0.y); pb[2] = f2bf(b0.z); pb[3] = f2bf(b0.w);
        pb[4] = f2bf(b1.x); pb[5] = f2bf(b1.y); pb[6] = f2bf(b1.z); pb[7] = f2bf(b1.w);
        *(short8*)&As[srow * 64 + chunk * 8] = pa;
        *(short8*)&Bs[srow * 64 + chunk * 8] = pb;
      }
    }
    __syncthreads();
#pragma unroll
    for (int ks = 0; ks < 2; ++ks) {
      short8 af[4], bfr[4];
#pragma unroll
      for (int m = 0; m < 4; ++m) {
        int row = wr * 64 + m * 16 + r15;
        int chunk = (ks * 4 + g) ^ (row & 7);
        af[m] = *(const short8*)&As[row * 64 + chunk * 8];
      }
#pragma unroll
      for (int n = 0; n < 4; ++n) {
        int col = wc * 64 + n * 16 + r15;
        int chunk = (ks * 4 + g) ^ (col & 7);
        bfr[n] = *(const short8*)&Bs[col * 64 + chunk * 8];
      }
#pragma unroll
      for (int m = 0; m < 4; ++m)
#pragma unroll
        for (int n = 0; n < 4; ++n)
          acc[m][n] = __builtin_amdgcn_mfma_f32_16x16x32_bf16(af[m], bfr[n], acc[m][n], 0, 0, 0);
    }
  }
  const size_t base = (size_t)bh * KSEL + rt * 128;
#pragma unroll
  for (int m = 0; m < 4; ++m) {
    int row0 = wr * 64 + m * 16 + g * 4;   // C/D: col=lane&15, row=(lane>>4)*4+reg
#pragma unroll
    for (int n = 0; n < 4; ++n) {
      int col = wc * 64 + n * 16 + r15;
#pragma unroll
      for (int r = 0; r < 4; ++r)
        dst[(base + row0 + r) * HDIM + col] = f2bf(acc[m][n][r]);
    }
  }
}

// ---------------- K4: MFMA flash attention over sorted selected rows ----------------
__global__ __launch_bounds__(256) void k_attn_mfma(const short* __restrict__ q_s,
    const short* __restrict__ k_s, const short* __restrict__ v_s,
    short* __restrict__ out_s) {
  __shared__ __align__(16) short Ks[64 * 128];    // [key][dim], chunk^=(key&7)
  __shared__ __align__(16) short Vt[128 * 64];    // [dim][key], chunk^=(dim&7)
  __shared__ __align__(16) short Pl[4 * 16 * 72]; // per-wave P tile, pad 72
  const int bh = blockIdx.x, qt = blockIdx.y;
  const int tid = threadIdx.x;
  const int w = tid >> 6, lane = tid & 63;
  const int g = lane >> 4, r15 = lane & 15;
  const size_t bhbase = (size_t)bh * KSEL * HDIM;
  const int r0 = qt * 64;
  const float scale = 0.08838834764831845f;  // 1/sqrt(128)

  short8 qf[4];
  {
    const short* qrow = q_s + bhbase + (size_t)(r0 + w * 16 + r15) * HDIM;
#pragma unroll
    for (int ks = 0; ks < 4; ++ks)
      qf[ks] = *(const short8*)(qrow + ks * 32 + g * 8);
  }
  f32x4 o[8];
#pragma unroll
  for (int n = 0; n < 8; ++n) o[n] = (f32x4){0.f, 0.f, 0.f, 0.f};
  float mrow[4] = {-INFINITY, -INFINITY, -INFINITY, -INFINITY};
  float lrow[4] = {0.f, 0.f, 0.f, 0.f};

  short* myP = &Pl[w * 16 * 72];
  const short* kbase0 = k_s + bhbase + (size_t)lane * HDIM + w * 32;
  const short* vbase0 = v_s + bhbase + (size_t)lane * HDIM + w * 32;

  for (int kt = 0; kt <= qt; ++kt) {
    __syncthreads();
    {
      const short* kb = kbase0 + (size_t)kt * 64 * HDIM;
      const short* vb = vbase0 + (size_t)kt * 64 * HDIM;
#pragma unroll
      for (int i8 = 0; i8 < 4; ++i8) {
        int chunk = w * 4 + i8;
        short8 kv = *(const short8*)(kb + i8 * 8);
        *(short8*)&Ks[lane * 128 + (chunk ^ (lane & 7)) * 8] = kv;
        short8 vv = *(const short8*)(vb + i8 * 8);
        int d0 = w * 32 + i8 * 8;
#pragma unroll
        for (int e = 0; e < 8; ++e) {
          int d = d0 + e;
          Vt[d * 64 + (((lane >> 3) ^ (d & 7)) << 3) + (lane & 7)] = vv[e];
        }
      }
    }
    __syncthreads();

    f32x4 s[4];
#pragma unroll
    for (int n = 0; n < 4; ++n) s[n] = (f32x4){0.f, 0.f, 0.f, 0.f};
#pragma unroll
    for (int ks = 0; ks < 4; ++ks) {
#pragma unroll
      for (int n = 0; n < 4; ++n) {
        int row = n * 16 + r15;
        short8 kf = *(const short8*)&Ks[row * 128 + ((ks * 4 + g) ^ (r15 & 7)) * 8];
        s[n] = __builtin_amdgcn_mfma_f32_16x16x32_bf16(qf[ks], kf, s[n], 0, 0, 0);
      }
    }

    const bool diag = (kt == qt);
    float sv[4][4];
#pragma unroll
    for (int n = 0; n < 4; ++n) {
      int key = kt * 64 + n * 16 + r15;
#pragma unroll
      for (int r = 0; r < 4; ++r) {
        float xv = s[n][r] * scale;
        int qrow = r0 + w * 16 + g * 4 + r;
        sv[n][r] = (diag && key > qrow) ? -INFINITY : xv;
      }
    }
    float corr[4];
#pragma unroll
    for (int r = 0; r < 4; ++r) {
      float tm = fmaxf(fmaxf(sv[0][r], sv[1][r]), fmaxf(sv[2][r], sv[3][r]));
#pragma unroll
      for (int off = 8; off; off >>= 1) tm = fmaxf(tm, __shfl_xor(tm, off));
      float newm = fmaxf(mrow[r], tm);
      corr[r] = __expf(mrow[r] - newm);
      mrow[r] = newm;
      float ps = 0.f;
#pragma unroll
      for (int n = 0; n < 4; ++n) {
        float pv = __expf(sv[n][r] - newm);
        sv[n][r] = pv;
        ps += pv;
      }
#pragma unroll
      for (int off = 8; off; off >>= 1) ps += __shfl_xor(ps, off);
      lrow[r] = lrow[r] * corr[r] + ps;
    }
    f32x4 corrv = {corr[0], corr[1], corr[2], corr[3]};
#pragma unroll
    for (int n = 0; n < 4; ++n)
#pragma unroll
      for (int r = 0; r < 4; ++r)
        myP[(g * 4 + r) * 72 + n * 16 + r15] = f2bf(sv[n][r]);
#pragma unroll
    for (int n = 0; n < 8; ++n) o[n] *= corrv;

    short8 pf[2];
#pragma unroll
    for (int ks = 0; ks < 2; ++ks)
      pf[ks] = *(const short8*)&myP[r15 * 72 + ks * 32 + g * 8];
#pragma unroll
    for (int ks = 0; ks < 2; ++ks)
#pragma unroll
      for (int n2 = 0; n2 < 8; ++n2) {
        int row = n2 * 16 + r15;
        short8 vf = *(const short8*)&Vt[row * 64 + ((ks * 4 + g) ^ (r15 & 7)) * 8];
        o[n2] = __builtin_amdgcn_mfma_f32_16x16x32_bf16(pf[ks], vf, o[n2], 0, 0, 0);
      }
  }

  float inv[4];
#pragma unroll
  for (int r = 0; r < 4; ++r) inv[r] = 1.f / lrow[r];
#pragma unroll
  for (int n2 = 0; n2 < 8; ++n2) {
#pragma unroll
    for (int r = 0; r < 4; ++r) {
      int qrow = r0 + w * 16 + g * 4 + r;
      out_s[bhbase + (size_t)qrow * HDIM + n2 * 16 + r15] = f2bf(o[n2][r] * inv[r]);
    }
  }
}

// ---------------- K5a: build inverse map inv[bh][t] = k or -1 (no atomics, deterministic) ----------------
__global__ __launch_bounds__(512) void k_build_inv(const int* __restrict__ idx,
                                                   int* __restrict__ inv) {
  int bh = blockIdx.x, tid = threadIdx.x;
  int* row = inv + (size_t)bh * TT;
  for (int i = tid; i < TT; i += 512) row[i] = -1;
  __syncthreads();
  row[idx[bh * KSEL + tid]] = tid;
}

// ---------------- K5b phase 1: compact product P[h,k,c] = out_s_h @ wo_h^T (one b) ----------------
__global__ __launch_bounds__(256) void k_oproj_p1(
    const short* __restrict__ out_s_b, const float* __restrict__ wo,
    short* __restrict__ P) {
  __shared__ __align__(16) short As[128 * 64];
  __shared__ __align__(16) short Bs[128 * 64];
  const int h = blockIdx.x, rt = blockIdx.y, ct = blockIdx.z;
  const int tid = threadIdx.x;
  const int lane = tid & 63, wid = tid >> 6;
  const int wr = wid >> 1, wc = wid & 1;
  const int srow = tid >> 1, khalf = tid & 1;
  const int rm = srow & 7;
  const short* aRow = out_s_b + ((size_t)h * KSEL + rt * 128 + srow) * HDIM + khalf * 32;
  const float* bRow = wo + ((size_t)(ct * 128 + srow)) * DD + h * HDIM + khalf * 32;
  f32x4 acc[4][4];
#pragma unroll
  for (int m = 0; m < 4; ++m)
#pragma unroll
    for (int n = 0; n < 4; ++n) acc[m][n] = (f32x4){0.f, 0.f, 0.f, 0.f};
  const int r15 = lane & 15, g = lane >> 4;
#pragma unroll
  for (int k0 = 0; k0 < HDIM; k0 += 64) {
    __syncthreads();
    {
      const short8* ap = (const short8*)(aRow + k0);
      const float4* bp = (const float4*)(bRow + k0);
      short8 av[4]; float4 bv[8];
#pragma unroll
      for (int i = 0; i < 4; ++i) av[i] = ap[i];
#pragma unroll
      for (int i = 0; i < 8; ++i) bv[i] = bp[i];
#pragma unroll
      for (int c = 0; c < 4; ++c) {
        int chunk = (khalf * 4 + c) ^ rm;
        float4 b0 = bv[2 * c], b1 = bv[2 * c + 1];
        short8 pb;
        pb[0] = f2bf(b0.x); pb[1] = f2bf(b0.y); pb[2] = f2bf(b0.z); pb[3] = f2bf(b0.w);
        pb[4] = f2bf(b1.x); pb[5] = f2bf(b1.y); pb[6] = f2bf(b1.z); pb[7] = f2bf(b1.w);
        *(short8*)&As[srow * 64 + chunk * 8] = av[c];
        *(short8*)&Bs[srow * 64 + chunk * 8] = pb;
      }
    }
    __syncthreads();
#pragma unroll
    for (int ks = 0; ks < 2; ++ks) {
      short8 af[4], bfr[4];
#pragma unroll
      for (int m = 0; m < 4; ++m) {
        int row = wr * 64 + m * 16 + r15;
        int chunk = (ks * 4 + g) ^ (row & 7);
        af[m] = *(const short8*)&As[row * 64 + chunk * 8];
      }
#pragma unroll
      for (int n = 0; n < 4; ++n) {
        int col = wc * 64 + n * 16 + r15;
        int chunk = (ks * 4 + g) ^ (col & 7);
        bfr[n] = *(const short8*)&Bs[col * 64 + chunk * 8];
      }
#pragma unroll
      for (int m = 0; m < 4; ++m)
#pragma unroll
        for (int n = 0; n < 4; ++n)
          acc[m][n] = __builtin_amdgcn_mfma_f32_16x16x32_bf16(af[m], bfr[n], acc[m][n], 0, 0, 0);
    }
  }
#pragma unroll
  for (int m = 0; m < 4; ++m) {
#pragma unroll
    for (int r = 0; r < 4; ++r) {
      int row = rt * 128 + wr * 64 + m * 16 + g * 4 + r;
#pragma unroll
      for (int n = 0; n < 4; ++n) {
        int col = ct * 128 + wc * 64 + n * 16 + r15;
        P[((size_t)h * KSEL + row) * DD + col] = f2bf(acc[m][n][r]);
      }
    }
  }
}

// ---------------- K5c phase 2: per-token gather-reduce over heads, write once ----------------
__global__ __launch_bounds__(256) void k_oproj_p2(const short* __restrict__ P,
    const int* __restrict__ inv_b, float* __restrict__ out_b) {
  const int t = blockIdx.x, tid = threadIdx.x;
  const int c0 = tid * 8;
  float acc[8] = {0.f, 0.f, 0.f, 0.f, 0.f, 0.f, 0.f, 0.f};
#pragma unroll
  for (int h = 0; h < HH; ++h) {
    int k = inv_b[h * TT + t];
    if (k >= 0) {
      short8 pv = *(const short8*)&P[((size_t)h * KSEL + k) * DD + c0];
#pragma unroll
      for (int e = 0; e < 8; ++e) acc[e] += bf2f(pv[e]);
    }
  }
  float4 o0 = {acc[0], acc[1], acc[2], acc[3]};
  float4 o1 = {acc[4], acc[5], acc[6], acc[7]};
  *(float4*)&out_b[(size_t)t * DD + c0] = o0;
  *(float4*)&out_b[(size_t)t * DD + c0 + 4] = o1;
}

extern "C" void kernel_launch(void* const* d_in, const int* in_sizes, int n_in,
                              void* d_out, int out_size, void* d_ws, size_t ws_size,
                              hipStream_t stream) {
  (void)in_sizes; (void)n_in; (void)out_size; (void)ws_size;
  const float* x  = (const float*)d_in[0];
  const float* wq = (const float*)d_in[1];
  const float* wk = (const float*)d_in[2];
  const float* wv = (const float*)d_in[3];
  const float* wo = (const float*)d_in[4];
  const float* wr = (const float*)d_in[5];
  float* out = (float*)d_out;

  // workspace layout (~70 MB, within round-1's proven footprint)
  float* scores = (float*)d_ws;                                  // B*H*T f32
  int*   idx    = (int*)(scores + (size_t)BB * HH * TT);         // B*H*K
  short* q_s    = (short*)(idx + NBH * KSEL);                    // bf16 bits
  short* k_s    = q_s + (size_t)NBH * KSEL * HDIM;
  short* v_s    = k_s + (size_t)NBH * KSEL * HDIM;
  short* out_s  = v_s + (size_t)NBH * KSEL * HDIM;
  int*   inv    = (int*)(out_s + (size_t)NBH * KSEL * HDIM);     // NBH*T
  short* P      = (short*)(inv + (size_t)NBH * TT);              // HH*KSEL*DD (per-b reuse)

  k_router<<<BB * TT / 4, 256, 0, stream>>>(x, wr, scores);
  k_topk<<<NBH, 512, 0, stream>>>(scores, idx);
  k_qkv_mfma<<<dim3(NBH, KSEL / 128, 3), 256, 0, stream>>>(x, wq, wk, wv, idx, q_s, k_s, v_s);
  k_attn_mfma<<<dim3(NBH, KSEL / 64), 256, 0, stream>>>(q_s, k_s, v_s, out_s);
  k_build_inv<<<NBH, 512, 0, stream>>>(idx, inv);
  for (int b = 0; b < BB; ++b) {
    k_oproj_p1<<<dim3(HH, KSEL / 128, DD / 128), 256, 0, stream>>>(
        out_s + (size_t)b * HH * KSEL * HDIM, wo, P);
    k_oproj_p2<<<TT, 256, 0, stream>>>(
        P, inv + (size_t)b * HH * TT, out + (size_t)b * TT * DD);
  }
}

// Round 5
// 471.830 us; speedup vs baseline: 6.3299x; 1.2169x over previous
//
#include <hip/hip_runtime.h>
#include <math.h>

#define BB 4
#define TT 4096
#define DD 2048
#define HH 16
#define HDIM 128
#define KSEL 512
#define NBH (BB*HH)

using short8  = __attribute__((ext_vector_type(8))) short;
using short4v = __attribute__((ext_vector_type(4))) short;
using f32x4   = __attribute__((ext_vector_type(4))) float;

__device__ __forceinline__ short f2bf(float f) {
  unsigned u = __float_as_uint(f);
  u += 0x7fffu + ((u >> 16) & 1u);   // round-nearest-even
  return (short)(u >> 16);
}
__device__ __forceinline__ float bf2f(short s) {
  return __uint_as_float(((unsigned)(unsigned short)s) << 16);
}

// ---------------- K0: one-time f32->bf16 weight conversion ----------------
__global__ __launch_bounds__(256) void k_cvt_w(const float* __restrict__ wq,
    const float* __restrict__ wk, const float* __restrict__ wv,
    const float* __restrict__ wo, short* __restrict__ dst) {
  const int wsel = blockIdx.y;
  const float* s = (wsel == 0) ? wq : (wsel == 1) ? wk : (wsel == 2) ? wv : wo;
  size_t base = (size_t)blockIdx.x * 2048 + (size_t)threadIdx.x * 8;
  float4 a = *(const float4*)(s + base);
  float4 b = *(const float4*)(s + base + 4);
  short8 o;
  o[0] = f2bf(a.x); o[1] = f2bf(a.y); o[2] = f2bf(a.z); o[3] = f2bf(a.w);
  o[4] = f2bf(b.x); o[5] = f2bf(b.y); o[6] = f2bf(b.z); o[7] = f2bf(b.w);
  *(short8*)&dst[(size_t)wsel * 4194304 + base] = o;
}

// ---------------- K1: router scores [B,H,T] (f32 — must match ref top-k set) ----------------
__global__ __launch_bounds__(256) void k_router(const float* __restrict__ x,
                                                const float* __restrict__ wr,
                                                float* __restrict__ scores) {
  int wave = threadIdx.x >> 6, lane = threadIdx.x & 63;
  int row = blockIdx.x * 4 + wave;          // b*T + t
  int b = row >> 12, t = row & (TT - 1);
  const float* xr = x + (size_t)row * DD;
  float xi[32];
#pragma unroll
  for (int i = 0; i < 32; ++i) xi[i] = xr[lane + i * 64];
  for (int h = 0; h < HH; ++h) {
    const float* w = wr + (size_t)h * DD;
    float acc = 0.f;
#pragma unroll
    for (int i = 0; i < 32; ++i) acc += xi[i] * w[lane + i * 64];
#pragma unroll
    for (int off = 32; off; off >>= 1) acc += __shfl_xor(acc, off);
    if (lane == 0) scores[((size_t)(b * HH + h)) * TT + t] = acc;
  }
}

// ---------------- K2: per-(b,h) top-512, output ascending by position ----------------
__global__ __launch_bounds__(512) void k_topk(const float* __restrict__ scores,
                                              int* __restrict__ idx) {
  __shared__ unsigned long long keys[TT];
  __shared__ unsigned tsel[KSEL];
  int bh = blockIdx.x, tid = threadIdx.x;
  const float* sc = scores + (size_t)bh * TT;
  for (int i = tid; i < TT; i += 512) {
    unsigned u = __float_as_uint(sc[i]);
    u = (u & 0x80000000u) ? ~u : (u | 0x80000000u);  // monotone map
    keys[i] = ((unsigned long long)u << 32) | (unsigned)(~i); // tie: lower i wins
  }
  __syncthreads();
  for (int k = 2; k <= TT; k <<= 1)
    for (int j = k >> 1; j > 0; j >>= 1) {
      for (int i = tid; i < TT; i += 512) {
        int ixj = i ^ j;
        if (ixj > i) {
          unsigned long long a = keys[i], c = keys[ixj];
          bool asc = ((i & k) == 0);
          if (asc ? (a > c) : (a < c)) { keys[i] = c; keys[ixj] = a; }
        }
      }
      __syncthreads();
    }
  if (tid < KSEL) tsel[tid] = ~((unsigned)keys[TT - KSEL + tid]);
  __syncthreads();
  for (int k = 2; k <= KSEL; k <<= 1)
    for (int j = k >> 1; j > 0; j >>= 1) {
      int i = tid, ixj = tid ^ j;
      if (ixj > i) {
        unsigned a = tsel[i], c = tsel[ixj];
        bool asc = ((i & k) == 0);
        if (asc ? (a > c) : (a < c)) { tsel[i] = c; tsel[ixj] = a; }
      }
      __syncthreads();
    }
  if (tid < KSEL) idx[bh * KSEL + tid] = (int)tsel[tid];
}

// ---------------- K3: merged gathered QKV projection via bf16 MFMA ----------------
// One block: 64 gathered rows x (q|k|v = 384 cols), K=2048. A staged once per K-step.
// XCD-chunked mapping: all 8 row-tiles of a (b,h) share one XCD's L2 (weight slice resident).
__global__ __launch_bounds__(256, 2) void k_qkv_mfma(
    const float* __restrict__ x, const short* __restrict__ wqb,
    const short* __restrict__ wkb, const short* __restrict__ wvb,
    const int* __restrict__ idx,
    short* __restrict__ q_s, short* __restrict__ k_s, short* __restrict__ v_s) {
  __shared__ __align__(16) short As[64 * 64];
  __shared__ __align__(16) short Bs[3][128 * 64];
  __shared__ int tIdx[64];
  const int L = blockIdx.x;
  const int bh = (L & 7) * 8 + (L >> 6);
  const int rt = (L >> 3) & 7;
  const int b = bh >> 4, h = bh & 15;
  const int tid = threadIdx.x;
  if (tid < 64) tIdx[tid] = idx[bh * KSEL + rt * 64 + tid];
  __syncthreads();
  const int lane = tid & 63, w = tid >> 6;
  const int g = lane >> 4, r15 = lane & 15;
  const int arow = tid >> 2, kq = tid & 3;       // A stage: 4 thr/row, 16 k each
  const int bcol = tid >> 1, khalf = tid & 1;    // B stage: 2 thr/col, 32 k each
  const float* aPtr = x + ((size_t)b * TT + tIdx[arow]) * DD + kq * 16;
  const size_t wOff = ((size_t)(h * HDIM + bcol)) * DD + khalf * 32;
  const short* wp0 = wqb + wOff;
  const short* wp1 = wkb + wOff;
  const short* wp2 = wvb + wOff;
  f32x4 acc[4][6];
#pragma unroll
  for (int m = 0; m < 4; ++m)
#pragma unroll
    for (int n = 0; n < 6; ++n) acc[m][n] = (f32x4){0.f, 0.f, 0.f, 0.f};
  const int rm = arow & 7, cm = bcol & 7;
  for (int k0 = 0; k0 < DD; k0 += 64) {
    __syncthreads();
    {
      float4 a0 = *(const float4*)(aPtr + k0);
      float4 a1 = *(const float4*)(aPtr + k0 + 4);
      float4 a2 = *(const float4*)(aPtr + k0 + 8);
      float4 a3 = *(const float4*)(aPtr + k0 + 12);
      short8 p0, p1;
      p0[0] = f2bf(a0.x); p0[1] = f2bf(a0.y); p0[2] = f2bf(a0.z); p0[3] = f2bf(a0.w);
      p0[4] = f2bf(a1.x); p0[5] = f2bf(a1.y); p0[6] = f2bf(a1.z); p0[7] = f2bf(a1.w);
      p1[0] = f2bf(a2.x); p1[1] = f2bf(a2.y); p1[2] = f2bf(a2.z); p1[3] = f2bf(a2.w);
      p1[4] = f2bf(a3.x); p1[5] = f2bf(a3.y); p1[6] = f2bf(a3.z); p1[7] = f2bf(a3.w);
      *(short8*)&As[arow * 64 + ((2 * kq) ^ rm) * 8] = p0;
      *(short8*)&As[arow * 64 + ((2 * kq + 1) ^ rm) * 8] = p1;
      const short8* s0 = (const short8*)(wp0 + k0);
      const short8* s1 = (const short8*)(wp1 + k0);
      const short8* s2 = (const short8*)(wp2 + k0);
#pragma unroll
      for (int c = 0; c < 4; ++c) {
        int slot = bcol * 64 + ((khalf * 4 + c) ^ cm) * 8;
        *(short8*)&Bs[0][slot] = s0[c];
        *(short8*)&Bs[1][slot] = s1[c];
        *(short8*)&Bs[2][slot] = s2[c];
      }
    }
    __syncthreads();
#pragma unroll
    for (int ks = 0; ks < 2; ++ks) {
      short8 af[4], bfr[6];
#pragma unroll
      for (int m = 0; m < 4; ++m) {
        int row = m * 16 + r15;
        af[m] = *(const short8*)&As[row * 64 + ((ks * 4 + g) ^ (row & 7)) * 8];
      }
#pragma unroll
      for (int n = 0; n < 6; ++n) {
        int nf = w * 6 + n;
        int colr = (nf & 7) * 16 + r15;
        bfr[n] = *(const short8*)&Bs[nf >> 3][colr * 64 + ((ks * 4 + g) ^ (colr & 7)) * 8];
      }
#pragma unroll
      for (int m = 0; m < 4; ++m)
#pragma unroll
        for (int n = 0; n < 6; ++n)
          acc[m][n] = __builtin_amdgcn_mfma_f32_16x16x32_bf16(af[m], bfr[n], acc[m][n], 0, 0, 0);
    }
  }
#pragma unroll
  for (int n = 0; n < 6; ++n) {
    int nf = w * 6 + n;
    int p = nf >> 3;
    short* dp = (p == 0) ? q_s : (p == 1) ? k_s : v_s;
    int col = (nf & 7) * 16 + r15;
#pragma unroll
    for (int m = 0; m < 4; ++m) {
      int row0 = rt * 64 + m * 16 + g * 4;
#pragma unroll
      for (int r = 0; r < 4; ++r)
        dp[((size_t)bh * KSEL + row0 + r) * HDIM + col] = f2bf(acc[m][n][r]);
    }
  }
}

// ---------------- K4: MFMA flash attention over sorted selected rows ----------------
__global__ __launch_bounds__(256) void k_attn_mfma(const short* __restrict__ q_s,
    const short* __restrict__ k_s, const short* __restrict__ v_s,
    short* __restrict__ out_s) {
  __shared__ __align__(16) short Ks[64 * 128];    // [key][dim], chunk^=(key&7)
  __shared__ __align__(16) short Vt[128 * 64];    // [dim][key], chunk^=(dim&7)
  __shared__ __align__(16) short Pl[4 * 16 * 72]; // per-wave P tile, pad 72
  const int bh = blockIdx.x, qt = blockIdx.y;
  const int tid = threadIdx.x;
  const int w = tid >> 6, lane = tid & 63;
  const int g = lane >> 4, r15 = lane & 15;
  const size_t bhbase = (size_t)bh * KSEL * HDIM;
  const int r0 = qt * 64;
  const float scale = 0.08838834764831845f;  // 1/sqrt(128)

  short8 qf[4];
  {
    const short* qrow = q_s + bhbase + (size_t)(r0 + w * 16 + r15) * HDIM;
#pragma unroll
    for (int ks = 0; ks < 4; ++ks)
      qf[ks] = *(const short8*)(qrow + ks * 32 + g * 8);
  }
  f32x4 o[8];
#pragma unroll
  for (int n = 0; n < 8; ++n) o[n] = (f32x4){0.f, 0.f, 0.f, 0.f};
  float mrow[4] = {-INFINITY, -INFINITY, -INFINITY, -INFINITY};
  float lrow[4] = {0.f, 0.f, 0.f, 0.f};

  short* myP = &Pl[w * 16 * 72];
  const short* kbase0 = k_s + bhbase + (size_t)lane * HDIM + w * 32;
  const short* vbase0 = v_s + bhbase + (size_t)lane * HDIM + w * 32;

  for (int kt = 0; kt <= qt; ++kt) {
    __syncthreads();
    {
      const short* kb = kbase0 + (size_t)kt * 64 * HDIM;
      const short* vb = vbase0 + (size_t)kt * 64 * HDIM;
#pragma unroll
      for (int i8 = 0; i8 < 4; ++i8) {
        int chunk = w * 4 + i8;
        short8 kv = *(const short8*)(kb + i8 * 8);
        *(short8*)&Ks[lane * 128 + (chunk ^ (lane & 7)) * 8] = kv;
        short8 vv = *(const short8*)(vb + i8 * 8);
        int d0 = w * 32 + i8 * 8;
#pragma unroll
        for (int e = 0; e < 8; ++e) {
          int d = d0 + e;
          Vt[d * 64 + (((lane >> 3) ^ (d & 7)) << 3) + (lane & 7)] = vv[e];
        }
      }
    }
    __syncthreads();

    f32x4 s[4];
#pragma unroll
    for (int n = 0; n < 4; ++n) s[n] = (f32x4){0.f, 0.f, 0.f, 0.f};
#pragma unroll
    for (int ks = 0; ks < 4; ++ks) {
#pragma unroll
      for (int n = 0; n < 4; ++n) {
        int row = n * 16 + r15;
        short8 kf = *(const short8*)&Ks[row * 128 + ((ks * 4 + g) ^ (r15 & 7)) * 8];
        s[n] = __builtin_amdgcn_mfma_f32_16x16x32_bf16(qf[ks], kf, s[n], 0, 0, 0);
      }
    }

    const bool diag = (kt == qt);
    float sv[4][4];
#pragma unroll
    for (int n = 0; n < 4; ++n) {
      int key = kt * 64 + n * 16 + r15;
#pragma unroll
      for (int r = 0; r < 4; ++r) {
        float xv = s[n][r] * scale;
        int qrow = r0 + w * 16 + g * 4 + r;
        sv[n][r] = (diag && key > qrow) ? -INFINITY : xv;
      }
    }
    float corr[4];
#pragma unroll
    for (int r = 0; r < 4; ++r) {
      float tm = fmaxf(fmaxf(sv[0][r], sv[1][r]), fmaxf(sv[2][r], sv[3][r]));
#pragma unroll
      for (int off = 8; off; off >>= 1) tm = fmaxf(tm, __shfl_xor(tm, off));
      float newm = fmaxf(mrow[r], tm);
      corr[r] = __expf(mrow[r] - newm);
      mrow[r] = newm;
      float ps = 0.f;
#pragma unroll
      for (int n = 0; n < 4; ++n) {
        float pv = __expf(sv[n][r] - newm);
        sv[n][r] = pv;
        ps += pv;
      }
#pragma unroll
      for (int off = 8; off; off >>= 1) ps += __shfl_xor(ps, off);
      lrow[r] = lrow[r] * corr[r] + ps;
    }
    f32x4 corrv = {corr[0], corr[1], corr[2], corr[3]};
#pragma unroll
    for (int n = 0; n < 4; ++n)
#pragma unroll
      for (int r = 0; r < 4; ++r)
        myP[(g * 4 + r) * 72 + n * 16 + r15] = f2bf(sv[n][r]);
#pragma unroll
    for (int n = 0; n < 8; ++n) o[n] *= corrv;

    short8 pf[2];
#pragma unroll
    for (int ks = 0; ks < 2; ++ks)
      pf[ks] = *(const short8*)&myP[r15 * 72 + ks * 32 + g * 8];
#pragma unroll
    for (int ks = 0; ks < 2; ++ks)
#pragma unroll
      for (int n2 = 0; n2 < 8; ++n2) {
        int row = n2 * 16 + r15;
        short8 vf = *(const short8*)&Vt[row * 64 + ((ks * 4 + g) ^ (r15 & 7)) * 8];
        o[n2] = __builtin_amdgcn_mfma_f32_16x16x32_bf16(pf[ks], vf, o[n2], 0, 0, 0);
      }
  }

  float inv[4];
#pragma unroll
  for (int r = 0; r < 4; ++r) inv[r] = 1.f / lrow[r];
#pragma unroll
  for (int n2 = 0; n2 < 8; ++n2) {
#pragma unroll
    for (int r = 0; r < 4; ++r) {
      int qrow = r0 + w * 16 + g * 4 + r;
      out_s[bhbase + (size_t)qrow * HDIM + n2 * 16 + r15] = f2bf(o[n2][r] * inv[r]);
    }
  }
}

// ---------------- K5a: build inverse map inv[bh][t] = k or -1 (no atomics, deterministic) ----------------
__global__ __launch_bounds__(512) void k_build_inv(const int* __restrict__ idx,
                                                   int* __restrict__ inv) {
  int bh = blockIdx.x, tid = threadIdx.x;
  int* row = inv + (size_t)bh * TT;
  for (int i = tid; i < TT; i += 512) row[i] = -1;
  __syncthreads();
  row[idx[bh * KSEL + tid]] = tid;
}

// ---------------- K5b phase 1: compact product P[h,k,c] = out_s_h @ wo_h^T (one b) ----------------
__global__ __launch_bounds__(256) void k_oproj_p1(
    const short* __restrict__ out_s_b, const short* __restrict__ wob,
    short* __restrict__ P) {
  __shared__ __align__(16) short As[128 * 64];
  __shared__ __align__(16) short Bs[128 * 64];
  const int h = blockIdx.x, rt = blockIdx.y, ct = blockIdx.z;
  const int tid = threadIdx.x;
  const int lane = tid & 63, wid = tid >> 6;
  const int wr = wid >> 1, wc = wid & 1;
  const int srow = tid >> 1, khalf = tid & 1;
  const int rm = srow & 7;
  const short* aRow = out_s_b + ((size_t)h * KSEL + rt * 128 + srow) * HDIM + khalf * 32;
  const short* bRow = wob + ((size_t)(ct * 128 + srow)) * DD + h * HDIM + khalf * 32;
  f32x4 acc[4][4];
#pragma unroll
  for (int m = 0; m < 4; ++m)
#pragma unroll
    for (int n = 0; n < 4; ++n) acc[m][n] = (f32x4){0.f, 0.f, 0.f, 0.f};
  const int r15 = lane & 15, g = lane >> 4;
#pragma unroll
  for (int k0 = 0; k0 < HDIM; k0 += 64) {
    __syncthreads();
    {
      const short8* ap = (const short8*)(aRow + k0);
      const short8* bp = (const short8*)(bRow + k0);
      short8 av[4], bv[4];
#pragma unroll
      for (int i = 0; i < 4; ++i) { av[i] = ap[i]; bv[i] = bp[i]; }
#pragma unroll
      for (int c = 0; c < 4; ++c) {
        int slot = srow * 64 + ((khalf * 4 + c) ^ rm) * 8;
        *(short8*)&As[slot] = av[c];
        *(short8*)&Bs[slot] = bv[c];
      }
    }
    __syncthreads();
#pragma unroll
    for (int ks = 0; ks < 2; ++ks) {
      short8 af[4], bfr[4];
#pragma unroll
      for (int m = 0; m < 4; ++m) {
        int row = wr * 64 + m * 16 + r15;
        int chunk = (ks * 4 + g) ^ (row & 7);
        af[m] = *(const short8*)&As[row * 64 + chunk * 8];
      }
#pragma unroll
      for (int n = 0; n < 4; ++n) {
        int col = wc * 64 + n * 16 + r15;
        int chunk = (ks * 4 + g) ^ (col & 7);
        bfr[n] = *(const short8*)&Bs[col * 64 + chunk * 8];
      }
#pragma unroll
      for (int m = 0; m < 4; ++m)
#pragma unroll
        for (int n = 0; n < 4; ++n)
          acc[m][n] = __builtin_amdgcn_mfma_f32_16x16x32_bf16(af[m], bfr[n], acc[m][n], 0, 0, 0);
    }
  }
#pragma unroll
  for (int m = 0; m < 4; ++m) {
#pragma unroll
    for (int r = 0; r < 4; ++r) {
      int row = rt * 128 + wr * 64 + m * 16 + g * 4 + r;
#pragma unroll
      for (int n = 0; n < 4; ++n) {
        int col = ct * 128 + wc * 64 + n * 16 + r15;
        P[((size_t)h * KSEL + row) * DD + col] = f2bf(acc[m][n][r]);
      }
    }
  }
}

// ---------------- K5c phase 2: per-token gather-reduce over heads, write once ----------------
__global__ __launch_bounds__(256) void k_oproj_p2(const short* __restrict__ P,
    const int* __restrict__ inv_b, float* __restrict__ out_b) {
  const int t = blockIdx.x, tid = threadIdx.x;
  const int c0 = tid * 8;
  float acc[8] = {0.f, 0.f, 0.f, 0.f, 0.f, 0.f, 0.f, 0.f};
#pragma unroll
  for (int h = 0; h < HH; ++h) {
    int k = inv_b[h * TT + t];
    if (k >= 0) {
      short8 pv = *(const short8*)&P[((size_t)h * KSEL + k) * DD + c0];
#pragma unroll
      for (int e = 0; e < 8; ++e) acc[e] += bf2f(pv[e]);
    }
  }
  float4 o0 = {acc[0], acc[1], acc[2], acc[3]};
  float4 o1 = {acc[4], acc[5], acc[6], acc[7]};
  *(float4*)&out_b[(size_t)t * DD + c0] = o0;
  *(float4*)&out_b[(size_t)t * DD + c0 + 4] = o1;
}

extern "C" void kernel_launch(void* const* d_in, const int* in_sizes, int n_in,
                              void* d_out, int out_size, void* d_ws, size_t ws_size,
                              hipStream_t stream) {
  (void)in_sizes; (void)n_in; (void)out_size; (void)ws_size;
  const float* x  = (const float*)d_in[0];
  const float* wq = (const float*)d_in[1];
  const float* wk = (const float*)d_in[2];
  const float* wv = (const float*)d_in[3];
  const float* wo = (const float*)d_in[4];
  const float* wr = (const float*)d_in[5];
  float* out = (float*)d_out;

  // workspace layout (~78 MB); P aliases q_s/k_s/v_s (dead after attn)
  char* ws = (char*)d_ws;
  float* scores = (float*)ws;                                  // 1 MB
  int*   idx    = (int*)(ws + 1048576);                        // 128 KB
  short* wqb    = (short*)(ws + 1179648);                      // 4x 8 MB bf16 weights
  short* wkb    = wqb + 4194304;
  short* wvb    = wkb + 4194304;
  short* wob    = wvb + 4194304;
  short* out_s  = wob + 4194304;                               // 8 MB
  int*   inv    = (int*)((char*)out_s + 8388608);              // 1 MB
  short* P      = (short*)((char*)inv + 1048576);              // 32 MB (per-b reuse)
  short* q_s    = P;
  short* k_s    = P + 4194304;
  short* v_s    = P + 8388608;

  k_cvt_w<<<dim3(2048, 4), 256, 0, stream>>>(wq, wk, wv, wo, wqb);
  k_router<<<BB * TT / 4, 256, 0, stream>>>(x, wr, scores);
  k_topk<<<NBH, 512, 0, stream>>>(scores, idx);
  k_qkv_mfma<<<512, 256, 0, stream>>>(x, wqb, wkb, wvb, idx, q_s, k_s, v_s);
  k_attn_mfma<<<dim3(NBH, KSEL / 64), 256, 0, stream>>>(q_s, k_s, v_s, out_s);
  k_build_inv<<<NBH, 512, 0, stream>>>(idx, inv);
  for (int b = 0; b < BB; ++b) {
    k_oproj_p1<<<dim3(HH, KSEL / 128, DD / 128), 256, 0, stream>>>(
        out_s + (size_t)b * HH * KSEL * HDIM, wob, P);
    k_oproj_p2<<<TT, 256, 0, stream>>>(
        P, inv + (size_t)b * HH * TT, out + (size_t)b * TT * DD);
  }
}

// Round 6
// 436.623 us; speedup vs baseline: 6.8403x; 1.0806x over previous
//
#include <hip/hip_runtime.h>
#include <math.h>

#define BB 4
#define TT 4096
#define DD 2048
#define HH 16
#define HDIM 128
#define KSEL 512
#define NBH (BB*HH)

using short8  = __attribute__((ext_vector_type(8))) short;
using short4v = __attribute__((ext_vector_type(4))) short;
using f32x4   = __attribute__((ext_vector_type(4))) float;

__device__ __forceinline__ short f2bf(float f) {
  unsigned u = __float_as_uint(f);
  u += 0x7fffu + ((u >> 16) & 1u);   // round-nearest-even
  return (short)(u >> 16);
}
__device__ __forceinline__ float bf2f(short s) {
  return __uint_as_float(((unsigned)(unsigned short)s) << 16);
}

// ---------------- K0: one-time f32->bf16 weight conversion ----------------
__global__ __launch_bounds__(256) void k_cvt_w(const float* __restrict__ wq,
    const float* __restrict__ wk, const float* __restrict__ wv,
    const float* __restrict__ wo, short* __restrict__ dst) {
  const int wsel = blockIdx.y;
  const float* s = (wsel == 0) ? wq : (wsel == 1) ? wk : (wsel == 2) ? wv : wo;
  size_t base = (size_t)blockIdx.x * 2048 + (size_t)threadIdx.x * 8;
  float4 a = *(const float4*)(s + base);
  float4 b = *(const float4*)(s + base + 4);
  short8 o;
  o[0] = f2bf(a.x); o[1] = f2bf(a.y); o[2] = f2bf(a.z); o[3] = f2bf(a.w);
  o[4] = f2bf(b.x); o[5] = f2bf(b.y); o[6] = f2bf(b.z); o[7] = f2bf(b.w);
  *(short8*)&dst[(size_t)wsel * 4194304 + base] = o;
}

// ---------------- K1: router scores via LDS-tiled split-K f32 GEMM ----------------
// Block: 256 thr, 256 tokens x 16 heads x 512-dim K-quarter. Thread: 4 tok x 4 heads.
// f32 throughout (score order-statistics too tight for bf16).
__global__ __launch_bounds__(256) void k_router2(const float* __restrict__ x,
    const float* __restrict__ wr, float* __restrict__ part) {
  __shared__ __align__(16) float Xs[256][36];
  __shared__ __align__(16) float Ws[16][36];
  const int tb = blockIdx.x, kq = blockIdx.y;
  const int tid = threadIdx.x;
  const int row0 = tb * 256;
  const int tq = tid >> 2;       // 0..63
  const int hq = tid & 3;
  float acc[4][4];
#pragma unroll
  for (int i = 0; i < 4; ++i)
#pragma unroll
    for (int j = 0; j < 4; ++j) acc[i][j] = 0.f;
  const int srr = tid >> 3, scc = (tid & 7) * 4;
  for (int c = 0; c < 16; ++c) {
    const int k0 = kq * 512 + c * 32;
    __syncthreads();
    {
#pragma unroll
      for (int i = 0; i < 8; ++i) {
        int r = srr + i * 32;
        float4 v = *(const float4*)(x + (size_t)(row0 + r) * DD + k0 + scc);
        *(float4*)&Xs[r][scc] = v;
      }
      if (tid < 128) {
        float4 v = *(const float4*)(wr + (size_t)(tid >> 3) * DD + k0 + (tid & 7) * 4);
        *(float4*)&Ws[tid >> 3][(tid & 7) * 4] = v;
      }
    }
    __syncthreads();
#pragma unroll
    for (int k4 = 0; k4 < 8; ++k4) {
      float4 xv[4], wv[4];
#pragma unroll
      for (int i = 0; i < 4; ++i) xv[i] = *(const float4*)&Xs[tq + i * 64][k4 * 4];
#pragma unroll
      for (int j = 0; j < 4; ++j) wv[j] = *(const float4*)&Ws[hq + j * 4][k4 * 4];
#pragma unroll
      for (int i = 0; i < 4; ++i)
#pragma unroll
        for (int j = 0; j < 4; ++j)
          acc[i][j] += xv[i].x * wv[j].x + xv[i].y * wv[j].y +
                       xv[i].z * wv[j].z + xv[i].w * wv[j].w;
    }
  }
#pragma unroll
  for (int i = 0; i < 4; ++i) {
    int tg = row0 + tq + i * 64;
    int b = tg >> 12, t = tg & (TT - 1);
#pragma unroll
    for (int j = 0; j < 4; ++j)
      part[((size_t)kq * NBH + (b * HH + hq + j * 4)) * TT + t] = acc[i][j];
  }
}

__global__ __launch_bounds__(256) void k_router_sum(const float* __restrict__ part,
                                                    float* __restrict__ scores) {
  size_t i = ((size_t)blockIdx.x * 256 + threadIdx.x) * 4;
  const size_t S = (size_t)NBH * TT;
  float4 a = *(const float4*)(part + i);
  float4 b = *(const float4*)(part + S + i);
  float4 c = *(const float4*)(part + 2 * S + i);
  float4 d = *(const float4*)(part + 3 * S + i);
  float4 o = {((a.x + b.x) + c.x) + d.x, ((a.y + b.y) + c.y) + d.y,
              ((a.z + b.z) + c.z) + d.z, ((a.w + b.w) + c.w) + d.w};
  *(float4*)(scores + i) = o;
}

// ---------------- K2: per-(b,h) top-512, output ascending by position ----------------
__global__ __launch_bounds__(512) void k_topk(const float* __restrict__ scores,
                                              int* __restrict__ idx) {
  __shared__ unsigned long long keys[TT];
  __shared__ unsigned tsel[KSEL];
  int bh = blockIdx.x, tid = threadIdx.x;
  const float* sc = scores + (size_t)bh * TT;
  for (int i = tid; i < TT; i += 512) {
    unsigned u = __float_as_uint(sc[i]);
    u = (u & 0x80000000u) ? ~u : (u | 0x80000000u);  // monotone map
    keys[i] = ((unsigned long long)u << 32) | (unsigned)(~i); // tie: lower i wins
  }
  __syncthreads();
  for (int k = 2; k <= TT; k <<= 1)
    for (int j = k >> 1; j > 0; j >>= 1) {
      for (int i = tid; i < TT; i += 512) {
        int ixj = i ^ j;
        if (ixj > i) {
          unsigned long long a = keys[i], c = keys[ixj];
          bool asc = ((i & k) == 0);
          if (asc ? (a > c) : (a < c)) { keys[i] = c; keys[ixj] = a; }
        }
      }
      __syncthreads();
    }
  if (tid < KSEL) tsel[tid] = ~((unsigned)keys[TT - KSEL + tid]);
  __syncthreads();
  for (int k = 2; k <= KSEL; k <<= 1)
    for (int j = k >> 1; j > 0; j >>= 1) {
      int i = tid, ixj = tid ^ j;
      if (ixj > i) {
        unsigned a = tsel[i], c = tsel[ixj];
        bool asc = ((i & k) == 0);
        if (asc ? (a > c) : (a < c)) { tsel[i] = c; tsel[ixj] = a; }
      }
      __syncthreads();
    }
  if (tid < KSEL) idx[bh * KSEL + tid] = (int)tsel[tid];
}

// ---------------- K3: merged gathered QKV projection via bf16 MFMA ----------------
// One block: 64 gathered rows x (q|k|v = 384 cols), K=2048. V written TRANSPOSED.
__global__ __launch_bounds__(256, 2) void k_qkv_mfma(
    const float* __restrict__ x, const short* __restrict__ wqb,
    const short* __restrict__ wkb, const short* __restrict__ wvb,
    const int* __restrict__ idx,
    short* __restrict__ q_s, short* __restrict__ k_s, short* __restrict__ v_t) {
  __shared__ __align__(16) short As[64 * 64];
  __shared__ __align__(16) short Bs[3][128 * 64];
  __shared__ int tIdx[64];
  const int L = blockIdx.x;
  const int bh = (L & 7) * 8 + (L >> 6);
  const int rt = (L >> 3) & 7;
  const int b = bh >> 4, h = bh & 15;
  const int tid = threadIdx.x;
  if (tid < 64) tIdx[tid] = idx[bh * KSEL + rt * 64 + tid];
  __syncthreads();
  const int lane = tid & 63, w = tid >> 6;
  const int g = lane >> 4, r15 = lane & 15;
  const int arow = tid >> 2, kq = tid & 3;       // A stage: 4 thr/row, 16 k each
  const int bcol = tid >> 1, khalf = tid & 1;    // B stage: 2 thr/col, 32 k each
  const float* aPtr = x + ((size_t)b * TT + tIdx[arow]) * DD + kq * 16;
  const size_t wOff = ((size_t)(h * HDIM + bcol)) * DD + khalf * 32;
  const short* wp0 = wqb + wOff;
  const short* wp1 = wkb + wOff;
  const short* wp2 = wvb + wOff;
  f32x4 acc[4][6];
#pragma unroll
  for (int m = 0; m < 4; ++m)
#pragma unroll
    for (int n = 0; n < 6; ++n) acc[m][n] = (f32x4){0.f, 0.f, 0.f, 0.f};
  const int rm = arow & 7, cm = bcol & 7;
  for (int k0 = 0; k0 < DD; k0 += 64) {
    __syncthreads();
    {
      float4 a0 = *(const float4*)(aPtr + k0);
      float4 a1 = *(const float4*)(aPtr + k0 + 4);
      float4 a2 = *(const float4*)(aPtr + k0 + 8);
      float4 a3 = *(const float4*)(aPtr + k0 + 12);
      short8 p0, p1;
      p0[0] = f2bf(a0.x); p0[1] = f2bf(a0.y); p0[2] = f2bf(a0.z); p0[3] = f2bf(a0.w);
      p0[4] = f2bf(a1.x); p0[5] = f2bf(a1.y); p0[6] = f2bf(a1.z); p0[7] = f2bf(a1.w);
      p1[0] = f2bf(a2.x); p1[1] = f2bf(a2.y); p1[2] = f2bf(a2.z); p1[3] = f2bf(a2.w);
      p1[4] = f2bf(a3.x); p1[5] = f2bf(a3.y); p1[6] = f2bf(a3.z); p1[7] = f2bf(a3.w);
      *(short8*)&As[arow * 64 + ((2 * kq) ^ rm) * 8] = p0;
      *(short8*)&As[arow * 64 + ((2 * kq + 1) ^ rm) * 8] = p1;
      const short8* s0 = (const short8*)(wp0 + k0);
      const short8* s1 = (const short8*)(wp1 + k0);
      const short8* s2 = (const short8*)(wp2 + k0);
#pragma unroll
      for (int c = 0; c < 4; ++c) {
        int slot = bcol * 64 + ((khalf * 4 + c) ^ cm) * 8;
        *(short8*)&Bs[0][slot] = s0[c];
        *(short8*)&Bs[1][slot] = s1[c];
        *(short8*)&Bs[2][slot] = s2[c];
      }
    }
    __syncthreads();
#pragma unroll
    for (int ks = 0; ks < 2; ++ks) {
      short8 af[4], bfr[6];
#pragma unroll
      for (int m = 0; m < 4; ++m) {
        int row = m * 16 + r15;
        af[m] = *(const short8*)&As[row * 64 + ((ks * 4 + g) ^ (row & 7)) * 8];
      }
#pragma unroll
      for (int n = 0; n < 6; ++n) {
        int nf = w * 6 + n;
        int colr = (nf & 7) * 16 + r15;
        bfr[n] = *(const short8*)&Bs[nf >> 3][colr * 64 + ((ks * 4 + g) ^ (colr & 7)) * 8];
      }
#pragma unroll
      for (int m = 0; m < 4; ++m)
#pragma unroll
        for (int n = 0; n < 6; ++n)
          acc[m][n] = __builtin_amdgcn_mfma_f32_16x16x32_bf16(af[m], bfr[n], acc[m][n], 0, 0, 0);
    }
  }
#pragma unroll
  for (int n = 0; n < 6; ++n) {
    int nf = w * 6 + n;
    int p = nf >> 3;
    int col = (nf & 7) * 16 + r15;
    if (p == 2) {
      // V transposed: v_t[bh][d=col][k], 4 consecutive k per (m) -> short4 store
#pragma unroll
      for (int m = 0; m < 4; ++m) {
        short4v pk;
#pragma unroll
        for (int r = 0; r < 4; ++r) pk[r] = f2bf(acc[m][n][r]);
        *(short4v*)&v_t[((size_t)bh * HDIM + col) * KSEL + rt * 64 + m * 16 + g * 4] = pk;
      }
    } else {
      short* dp = (p == 0) ? q_s : k_s;
#pragma unroll
      for (int m = 0; m < 4; ++m) {
        int row0 = rt * 64 + m * 16 + g * 4;
#pragma unroll
        for (int r = 0; r < 4; ++r)
          dp[((size_t)bh * KSEL + row0 + r) * HDIM + col] = f2bf(acc[m][n][r]);
      }
    }
  }
}

// ---------------- K4: MFMA flash attention over sorted selected rows ----------------
__global__ __launch_bounds__(256) void k_attn_mfma(const short* __restrict__ q_s,
    const short* __restrict__ k_s, const short* __restrict__ v_t,
    short* __restrict__ out_s) {
  __shared__ __align__(16) short Ks[64 * 128];    // [key][dim], chunk^=(key&7)
  __shared__ __align__(16) short Vt[128 * 64];    // [dim][key], chunk^=(dim&7)
  __shared__ __align__(16) short Pl[4 * 16 * 72]; // per-wave P tile, pad 72
  const int bh = blockIdx.x, qt = blockIdx.y;
  const int tid = threadIdx.x;
  const int w = tid >> 6, lane = tid & 63;
  const int g = lane >> 4, r15 = lane & 15;
  const size_t bhbase = (size_t)bh * KSEL * HDIM;
  const int r0 = qt * 64;
  const float scale = 0.08838834764831845f;  // 1/sqrt(128)

  short8 qf[4];
  {
    const short* qrow = q_s + bhbase + (size_t)(r0 + w * 16 + r15) * HDIM;
#pragma unroll
    for (int ks = 0; ks < 4; ++ks)
      qf[ks] = *(const short8*)(qrow + ks * 32 + g * 8);
  }
  f32x4 o[8];
#pragma unroll
  for (int n = 0; n < 8; ++n) o[n] = (f32x4){0.f, 0.f, 0.f, 0.f};
  float mrow[4] = {-INFINITY, -INFINITY, -INFINITY, -INFINITY};
  float lrow[4] = {0.f, 0.f, 0.f, 0.f};

  short* myP = &Pl[w * 16 * 72];
  const int krow = tid >> 2, kq4 = tid & 3;   // K stage: 4 thr/row, 32 shorts each
  const int vd = tid >> 1, vh = tid & 1;      // V stage: 2 thr/dim, 32 shorts each
  const short* kgb = k_s + bhbase + (size_t)krow * HDIM + kq4 * 32;
  const short* vgb = v_t + (size_t)bh * HDIM * KSEL + (size_t)vd * KSEL + vh * 32;

  for (int kt = 0; kt <= qt; ++kt) {
    int l0 = kt * 64;
    __syncthreads();
    {
      const short8* ksrc = (const short8*)(kgb + (size_t)l0 * HDIM);
      const short8* vsrc = (const short8*)(vgb + l0);
#pragma unroll
      for (int j = 0; j < 4; ++j) {
        *(short8*)&Ks[krow * 128 + (((kq4 * 4 + j) ^ (krow & 7)) << 3)] = ksrc[j];
        *(short8*)&Vt[vd * 64 + (((vh * 4 + j) ^ (vd & 7)) << 3)] = vsrc[j];
      }
    }
    __syncthreads();

    f32x4 s[4];
#pragma unroll
    for (int n = 0; n < 4; ++n) s[n] = (f32x4){0.f, 0.f, 0.f, 0.f};
#pragma unroll
    for (int ks = 0; ks < 4; ++ks) {
#pragma unroll
      for (int n = 0; n < 4; ++n) {
        int row = n * 16 + r15;
        short8 kf = *(const short8*)&Ks[row * 128 + ((ks * 4 + g) ^ (r15 & 7)) * 8];
        s[n] = __builtin_amdgcn_mfma_f32_16x16x32_bf16(qf[ks], kf, s[n], 0, 0, 0);
      }
    }

    const bool diag = (kt == qt);
    float sv[4][4];
#pragma unroll
    for (int n = 0; n < 4; ++n) {
      int key = kt * 64 + n * 16 + r15;
#pragma unroll
      for (int r = 0; r < 4; ++r) {
        float xv = s[n][r] * scale;
        int qrow = r0 + w * 16 + g * 4 + r;
        sv[n][r] = (diag && key > qrow) ? -INFINITY : xv;
      }
    }
    float corr[4];
#pragma unroll
    for (int r = 0; r < 4; ++r) {
      float tm = fmaxf(fmaxf(sv[0][r], sv[1][r]), fmaxf(sv[2][r], sv[3][r]));
#pragma unroll
      for (int off = 8; off; off >>= 1) tm = fmaxf(tm, __shfl_xor(tm, off));
      float newm = fmaxf(mrow[r], tm);
      corr[r] = __expf(mrow[r] - newm);
      mrow[r] = newm;
      float ps = 0.f;
#pragma unroll
      for (int n = 0; n < 4; ++n) {
        float pv = __expf(sv[n][r] - newm);
        sv[n][r] = pv;
        ps += pv;
      }
#pragma unroll
      for (int off = 8; off; off >>= 1) ps += __shfl_xor(ps, off);
      lrow[r] = lrow[r] * corr[r] + ps;
    }
    f32x4 corrv = {corr[0], corr[1], corr[2], corr[3]};
#pragma unroll
    for (int n = 0; n < 4; ++n)
#pragma unroll
      for (int r = 0; r < 4; ++r)
        myP[(g * 4 + r) * 72 + n * 16 + r15] = f2bf(sv[n][r]);
#pragma unroll
    for (int n = 0; n < 8; ++n) o[n] *= corrv;

    short8 pf[2];
#pragma unroll
    for (int ks = 0; ks < 2; ++ks)
      pf[ks] = *(const short8*)&myP[r15 * 72 + ks * 32 + g * 8];
#pragma unroll
    for (int ks = 0; ks < 2; ++ks)
#pragma unroll
      for (int n2 = 0; n2 < 8; ++n2) {
        int row = n2 * 16 + r15;
        short8 vf = *(const short8*)&Vt[row * 64 + ((ks * 4 + g) ^ (r15 & 7)) * 8];
        o[n2] = __builtin_amdgcn_mfma_f32_16x16x32_bf16(pf[ks], vf, o[n2], 0, 0, 0);
      }
  }

  float inv[4];
#pragma unroll
  for (int r = 0; r < 4; ++r) inv[r] = 1.f / lrow[r];
#pragma unroll
  for (int n2 = 0; n2 < 8; ++n2) {
#pragma unroll
    for (int r = 0; r < 4; ++r) {
      int qrow = r0 + w * 16 + g * 4 + r;
      out_s[bhbase + (size_t)qrow * HDIM + n2 * 16 + r15] = f2bf(o[n2][r] * inv[r]);
    }
  }
}

// ---------------- K5a: build inverse map inv[bh][t] = k or -1 ----------------
__global__ __launch_bounds__(512) void k_build_inv(const int* __restrict__ idx,
                                                   int* __restrict__ inv) {
  int bh = blockIdx.x, tid = threadIdx.x;
  int* row = inv + (size_t)bh * TT;
  for (int i = tid; i < TT; i += 512) row[i] = -1;
  __syncthreads();
  row[idx[bh * KSEL + tid]] = tid;
}

// ---------------- K5b phase 1: compact product P[h,k,c] = out_s_h @ wo_h^T (one b) ----------------
__global__ __launch_bounds__(256) void k_oproj_p1(
    const short* __restrict__ out_s_b, const short* __restrict__ wob,
    short* __restrict__ P) {
  __shared__ __align__(16) short As[128 * 64];
  __shared__ __align__(16) short Bs[128 * 64];
  const int h = blockIdx.x, rt = blockIdx.y, ct = blockIdx.z;
  const int tid = threadIdx.x;
  const int lane = tid & 63, wid = tid >> 6;
  const int wr = wid >> 1, wc = wid & 1;
  const int srow = tid >> 1, khalf = tid & 1;
  const int rm = srow & 7;
  const short* aRow = out_s_b + ((size_t)h * KSEL + rt * 128 + srow) * HDIM + khalf * 32;
  const short* bRow = wob + ((size_t)(ct * 128 + srow)) * DD + h * HDIM + khalf * 32;
  f32x4 acc[4][4];
#pragma unroll
  for (int m = 0; m < 4; ++m)
#pragma unroll
    for (int n = 0; n < 4; ++n) acc[m][n] = (f32x4){0.f, 0.f, 0.f, 0.f};
  const int r15 = lane & 15, g = lane >> 4;
#pragma unroll
  for (int k0 = 0; k0 < HDIM; k0 += 64) {
    __syncthreads();
    {
      const short8* ap = (const short8*)(aRow + k0);
      const short8* bp = (const short8*)(bRow + k0);
      short8 av[4], bv[4];
#pragma unroll
      for (int i = 0; i < 4; ++i) { av[i] = ap[i]; bv[i] = bp[i]; }
#pragma unroll
      for (int c = 0; c < 4; ++c) {
        int slot = srow * 64 + ((khalf * 4 + c) ^ rm) * 8;
        *(short8*)&As[slot] = av[c];
        *(short8*)&Bs[slot] = bv[c];
      }
    }
    __syncthreads();
#pragma unroll
    for (int ks = 0; ks < 2; ++ks) {
      short8 af[4], bfr[4];
#pragma unroll
      for (int m = 0; m < 4; ++m) {
        int row = wr * 64 + m * 16 + r15;
        int chunk = (ks * 4 + g) ^ (row & 7);
        af[m] = *(const short8*)&As[row * 64 + chunk * 8];
      }
#pragma unroll
      for (int n = 0; n < 4; ++n) {
        int col = wc * 64 + n * 16 + r15;
        int chunk = (ks * 4 + g) ^ (col & 7);
        bfr[n] = *(const short8*)&Bs[col * 64 + chunk * 8];
      }
#pragma unroll
      for (int m = 0; m < 4; ++m)
#pragma unroll
        for (int n = 0; n < 4; ++n)
          acc[m][n] = __builtin_amdgcn_mfma_f32_16x16x32_bf16(af[m], bfr[n], acc[m][n], 0, 0, 0);
    }
  }
#pragma unroll
  for (int m = 0; m < 4; ++m) {
#pragma unroll
    for (int r = 0; r < 4; ++r) {
      int row = rt * 128 + wr * 64 + m * 16 + g * 4 + r;
#pragma unroll
      for (int n = 0; n < 4; ++n) {
        int col = ct * 128 + wc * 64 + n * 16 + r15;
        P[((size_t)h * KSEL + row) * DD + col] = f2bf(acc[m][n][r]);
      }
    }
  }
}

// ---------------- K5c phase 2: per-token gather-reduce over heads, write once ----------------
__global__ __launch_bounds__(256) void k_oproj_p2(const short* __restrict__ P,
    const int* __restrict__ inv_b, float* __restrict__ out_b) {
  const int t = blockIdx.x, tid = threadIdx.x;
  const int c0 = tid * 8;
  float acc[8] = {0.f, 0.f, 0.f, 0.f, 0.f, 0.f, 0.f, 0.f};
#pragma unroll
  for (int h = 0; h < HH; ++h) {
    int k = inv_b[h * TT + t];
    if (k >= 0) {
      short8 pv = *(const short8*)&P[((size_t)h * KSEL + k) * DD + c0];
#pragma unroll
      for (int e = 0; e < 8; ++e) acc[e] += bf2f(pv[e]);
    }
  }
  float4 o0 = {acc[0], acc[1], acc[2], acc[3]};
  float4 o1 = {acc[4], acc[5], acc[6], acc[7]};
  *(float4*)&out_b[(size_t)t * DD + c0] = o0;
  *(float4*)&out_b[(size_t)t * DD + c0 + 4] = o1;
}

extern "C" void kernel_launch(void* const* d_in, const int* in_sizes, int n_in,
                              void* d_out, int out_size, void* d_ws, size_t ws_size,
                              hipStream_t stream) {
  (void)in_sizes; (void)n_in; (void)out_size; (void)ws_size;
  const float* x  = (const float*)d_in[0];
  const float* wq = (const float*)d_in[1];
  const float* wk = (const float*)d_in[2];
  const float* wv = (const float*)d_in[3];
  const float* wo = (const float*)d_in[4];
  const float* wr = (const float*)d_in[5];
  float* out = (float*)d_out;

  // workspace layout (~74 MB); P aliases q_s/k_s/v_t (dead after attn);
  // router partials alias P region too (dead before qkv writes it).
  char* ws = (char*)d_ws;
  float* scores = (float*)ws;                                  // 1 MB
  int*   idx    = (int*)(ws + 1048576);                        // 128 KB
  short* wqb    = (short*)(ws + 1179648);                      // 4x 8 MB bf16 weights
  short* wkb    = wqb + 4194304;
  short* wvb    = wkb + 4194304;
  short* wob    = wvb + 4194304;
  short* out_s  = wob + 4194304;                               // 8 MB
  int*   inv    = (int*)((char*)out_s + 8388608);              // 1 MB
  short* P      = (short*)((char*)inv + 1048576);              // 32 MB (per-b reuse)
  short* q_s    = P;
  short* k_s    = P + 4194304;
  short* v_t    = P + 8388608;
  float* part   = (float*)P;                                   // 4 MB (router partials)

  k_cvt_w<<<dim3(2048, 4), 256, 0, stream>>>(wq, wk, wv, wo, wqb);
  k_router2<<<dim3(64, 4), 256, 0, stream>>>(x, wr, part);
  k_router_sum<<<256, 256, 0, stream>>>(part, scores);
  k_topk<<<NBH, 512, 0, stream>>>(scores, idx);
  k_qkv_mfma<<<512, 256, 0, stream>>>(x, wqb, wkb, wvb, idx, q_s, k_s, v_t);
  k_attn_mfma<<<dim3(NBH, KSEL / 64), 256, 0, stream>>>(q_s, k_s, v_t, out_s);
  k_build_inv<<<NBH, 512, 0, stream>>>(idx, inv);
  for (int b = 0; b < BB; ++b) {
    k_oproj_p1<<<dim3(HH, KSEL / 128, DD / 128), 256, 0, stream>>>(
        out_s + (size_t)b * HH * KSEL * HDIM, wob, P);
    k_oproj_p2<<<TT, 256, 0, stream>>>(
        P, inv + (size_t)b * HH * TT, out + (size_t)b * TT * DD);
  }
}

// Round 7
// 389.576 us; speedup vs baseline: 7.6663x; 1.1208x over previous
//
#include <hip/hip_runtime.h>
#include <math.h>

#define BB 4
#define TT 4096
#define DD 2048
#define HH 16
#define HDIM 128
#define KSEL 512
#define NBH (BB*HH)

using short8  = __attribute__((ext_vector_type(8))) short;
using short4v = __attribute__((ext_vector_type(4))) short;
using f32x4   = __attribute__((ext_vector_type(4))) float;

__device__ __forceinline__ short f2bf(float f) {
  unsigned u = __float_as_uint(f);
  u += 0x7fffu + ((u >> 16) & 1u);   // round-nearest-even
  return (short)(u >> 16);
}
__device__ __forceinline__ float bf2f(short s) {
  return __uint_as_float(((unsigned)(unsigned short)s) << 16);
}

// async global->LDS, 16B per lane; LDS dest wave-uniform base + lane*16
__device__ __forceinline__ void gload16(const short* g, short* l) {
  __builtin_amdgcn_global_load_lds(
      (const __attribute__((address_space(1))) void*)g,
      (__attribute__((address_space(3))) void*)l, 16, 0, 0);
}

// ---------------- K0: one-time f32->bf16 weight conversion ----------------
__global__ __launch_bounds__(256) void k_cvt_w(const float* __restrict__ wq,
    const float* __restrict__ wk, const float* __restrict__ wv,
    const float* __restrict__ wo, short* __restrict__ dst) {
  const int wsel = blockIdx.y;
  const float* s = (wsel == 0) ? wq : (wsel == 1) ? wk : (wsel == 2) ? wv : wo;
  size_t base = (size_t)blockIdx.x * 2048 + (size_t)threadIdx.x * 8;
  float4 a = *(const float4*)(s + base);
  float4 b = *(const float4*)(s + base + 4);
  short8 o;
  o[0] = f2bf(a.x); o[1] = f2bf(a.y); o[2] = f2bf(a.z); o[3] = f2bf(a.w);
  o[4] = f2bf(b.x); o[5] = f2bf(b.y); o[6] = f2bf(b.z); o[7] = f2bf(b.w);
  *(short8*)&dst[(size_t)wsel * 4194304 + base] = o;
}

// ---------------- K1: router scores via LDS-tiled split-K f32 GEMM ----------------
__global__ __launch_bounds__(256) void k_router2(const float* __restrict__ x,
    const float* __restrict__ wr, float* __restrict__ part) {
  __shared__ __align__(16) float Xs[256][36];
  __shared__ __align__(16) float Ws[16][36];
  const int tb = blockIdx.x, kq = blockIdx.y;
  const int tid = threadIdx.x;
  const int row0 = tb * 256;
  const int tq = tid >> 2;       // 0..63
  const int hq = tid & 3;
  float acc[4][4];
#pragma unroll
  for (int i = 0; i < 4; ++i)
#pragma unroll
    for (int j = 0; j < 4; ++j) acc[i][j] = 0.f;
  const int srr = tid >> 3, scc = (tid & 7) * 4;
  for (int c = 0; c < 16; ++c) {
    const int k0 = kq * 512 + c * 32;
    __syncthreads();
    {
#pragma unroll
      for (int i = 0; i < 8; ++i) {
        int r = srr + i * 32;
        float4 v = *(const float4*)(x + (size_t)(row0 + r) * DD + k0 + scc);
        *(float4*)&Xs[r][scc] = v;
      }
      if (tid < 128) {
        float4 v = *(const float4*)(wr + (size_t)(tid >> 3) * DD + k0 + (tid & 7) * 4);
        *(float4*)&Ws[tid >> 3][(tid & 7) * 4] = v;
      }
    }
    __syncthreads();
#pragma unroll
    for (int k4 = 0; k4 < 8; ++k4) {
      float4 xv[4], wv[4];
#pragma unroll
      for (int i = 0; i < 4; ++i) xv[i] = *(const float4*)&Xs[tq + i * 64][k4 * 4];
#pragma unroll
      for (int j = 0; j < 4; ++j) wv[j] = *(const float4*)&Ws[hq + j * 4][k4 * 4];
#pragma unroll
      for (int i = 0; i < 4; ++i)
#pragma unroll
        for (int j = 0; j < 4; ++j)
          acc[i][j] += xv[i].x * wv[j].x + xv[i].y * wv[j].y +
                       xv[i].z * wv[j].z + xv[i].w * wv[j].w;
    }
  }
#pragma unroll
  for (int i = 0; i < 4; ++i) {
    int tg = row0 + tq + i * 64;
    int b = tg >> 12, t = tg & (TT - 1);
#pragma unroll
    for (int j = 0; j < 4; ++j)
      part[((size_t)kq * NBH + (b * HH + hq + j * 4)) * TT + t] = acc[i][j];
  }
}

__global__ __launch_bounds__(256) void k_router_sum(const float* __restrict__ part,
                                                    float* __restrict__ scores) {
  size_t i = ((size_t)blockIdx.x * 256 + threadIdx.x) * 4;
  const size_t S = (size_t)NBH * TT;
  float4 a = *(const float4*)(part + i);
  float4 b = *(const float4*)(part + S + i);
  float4 c = *(const float4*)(part + 2 * S + i);
  float4 d = *(const float4*)(part + 3 * S + i);
  float4 o = {((a.x + b.x) + c.x) + d.x, ((a.y + b.y) + c.y) + d.y,
              ((a.z + b.z) + c.z) + d.z, ((a.w + b.w) + c.w) + d.w};
  *(float4*)(scores + i) = o;
}

// ---------------- K2: per-(b,h) top-512, output ascending by position ----------------
__global__ __launch_bounds__(512) void k_topk(const float* __restrict__ scores,
                                              int* __restrict__ idx) {
  __shared__ unsigned long long keys[TT];
  __shared__ unsigned tsel[KSEL];
  int bh = blockIdx.x, tid = threadIdx.x;
  const float* sc = scores + (size_t)bh * TT;
  for (int i = tid; i < TT; i += 512) {
    unsigned u = __float_as_uint(sc[i]);
    u = (u & 0x80000000u) ? ~u : (u | 0x80000000u);  // monotone map
    keys[i] = ((unsigned long long)u << 32) | (unsigned)(~i); // tie: lower i wins
  }
  __syncthreads();
  for (int k = 2; k <= TT; k <<= 1)
    for (int j = k >> 1; j > 0; j >>= 1) {
      for (int i = tid; i < TT; i += 512) {
        int ixj = i ^ j;
        if (ixj > i) {
          unsigned long long a = keys[i], c = keys[ixj];
          bool asc = ((i & k) == 0);
          if (asc ? (a > c) : (a < c)) { keys[i] = c; keys[ixj] = a; }
        }
      }
      __syncthreads();
    }
  if (tid < KSEL) tsel[tid] = ~((unsigned)keys[TT - KSEL + tid]);
  __syncthreads();
  for (int k = 2; k <= KSEL; k <<= 1)
    for (int j = k >> 1; j > 0; j >>= 1) {
      int i = tid, ixj = tid ^ j;
      if (ixj > i) {
        unsigned a = tsel[i], c = tsel[ixj];
        bool asc = ((i & k) == 0);
        if (asc ? (a > c) : (a < c)) { tsel[i] = c; tsel[ixj] = a; }
      }
      __syncthreads();
    }
  if (tid < KSEL) idx[bh * KSEL + tid] = (int)tsel[tid];
}

// ---------------- K3: merged gathered QKV projection via bf16 MFMA ----------------
// B staged via global_load_lds (pre-swizzled source); A reg-staged (f32->bf16 cvt).
__global__ __launch_bounds__(256, 2) void k_qkv_mfma(
    const float* __restrict__ x, const short* __restrict__ wqb,
    const short* __restrict__ wkb, const short* __restrict__ wvb,
    const int* __restrict__ idx,
    short* __restrict__ q_s, short* __restrict__ k_s, short* __restrict__ v_t) {
  __shared__ __align__(16) short As[64 * 64];
  __shared__ __align__(16) short Bs[3][128 * 64];
  __shared__ int tIdx[64];
  const int L = blockIdx.x;
  const int bh = (L & 7) * 8 + (L >> 6);
  const int rt = (L >> 3) & 7;
  const int b = bh >> 4, h = bh & 15;
  const int tid = threadIdx.x;
  if (tid < 64) tIdx[tid] = idx[bh * KSEL + rt * 64 + tid];
  __syncthreads();
  const int lane = tid & 63, w = tid >> 6;
  const int g = lane >> 4, r15 = lane & 15;
  const int arow = tid >> 2, kq = tid & 3;       // A stage: 4 thr/row, 16 k each
  const int lcol8 = lane >> 3, lslot = lane & 7; // B stage lane mapping
  const float* aPtr = x + ((size_t)b * TT + tIdx[arow]) * DD + kq * 16;
  f32x4 acc[4][6];
#pragma unroll
  for (int m = 0; m < 4; ++m)
#pragma unroll
    for (int n = 0; n < 6; ++n) acc[m][n] = (f32x4){0.f, 0.f, 0.f, 0.f};
  const int rm = arow & 7;
  for (int k0 = 0; k0 < DD; k0 += 64) {
    __syncthreads();
    {
      // A: reg-stage + cvt + swizzled ds_write
      float4 a0 = *(const float4*)(aPtr + k0);
      float4 a1 = *(const float4*)(aPtr + k0 + 4);
      float4 a2 = *(const float4*)(aPtr + k0 + 8);
      float4 a3 = *(const float4*)(aPtr + k0 + 12);
      short8 p0, p1;
      p0[0] = f2bf(a0.x); p0[1] = f2bf(a0.y); p0[2] = f2bf(a0.z); p0[3] = f2bf(a0.w);
      p0[4] = f2bf(a1.x); p0[5] = f2bf(a1.y); p0[6] = f2bf(a1.z); p0[7] = f2bf(a1.w);
      p1[0] = f2bf(a2.x); p1[1] = f2bf(a2.y); p1[2] = f2bf(a2.z); p1[3] = f2bf(a2.w);
      p1[4] = f2bf(a3.x); p1[5] = f2bf(a3.y); p1[6] = f2bf(a3.z); p1[7] = f2bf(a3.w);
      *(short8*)&As[arow * 64 + ((2 * kq) ^ rm) * 8] = p0;
      *(short8*)&As[arow * 64 + ((2 * kq + 1) ^ rm) * 8] = p1;
      // B: async global->LDS, linear dest + inverse-swizzled source
#pragma unroll
      for (int t = 0; t < 12; ++t) {
        int gi = w * 12 + t;
        int p = gi >> 4;
        int c0 = (gi & 15) << 3;
        int col = c0 + lcol8;
        const short* wsrc = (p == 0 ? wqb : p == 1 ? wkb : wvb)
                          + ((size_t)(h * HDIM + col)) * DD + k0 + ((lslot ^ (col & 7)) << 3);
        gload16(wsrc, &Bs[p][c0 * 64]);
      }
    }
    __syncthreads();
#pragma unroll
    for (int ks = 0; ks < 2; ++ks) {
      short8 af[4], bfr[6];
#pragma unroll
      for (int m = 0; m < 4; ++m) {
        int row = m * 16 + r15;
        af[m] = *(const short8*)&As[row * 64 + ((ks * 4 + g) ^ (row & 7)) * 8];
      }
#pragma unroll
      for (int n = 0; n < 6; ++n) {
        int nf = w * 6 + n;
        int colr = (nf & 7) * 16 + r15;
        bfr[n] = *(const short8*)&Bs[nf >> 3][colr * 64 + ((ks * 4 + g) ^ (colr & 7)) * 8];
      }
#pragma unroll
      for (int m = 0; m < 4; ++m)
#pragma unroll
        for (int n = 0; n < 6; ++n)
          acc[m][n] = __builtin_amdgcn_mfma_f32_16x16x32_bf16(af[m], bfr[n], acc[m][n], 0, 0, 0);
    }
  }
#pragma unroll
  for (int n = 0; n < 6; ++n) {
    int nf = w * 6 + n;
    int p = nf >> 3;
    int col = (nf & 7) * 16 + r15;
    if (p == 2) {
#pragma unroll
      for (int m = 0; m < 4; ++m) {
        short4v pk;
#pragma unroll
        for (int r = 0; r < 4; ++r) pk[r] = f2bf(acc[m][n][r]);
        *(short4v*)&v_t[((size_t)bh * HDIM + col) * KSEL + rt * 64 + m * 16 + g * 4] = pk;
      }
    } else {
      short* dp = (p == 0) ? q_s : k_s;
#pragma unroll
      for (int m = 0; m < 4; ++m) {
        int row0 = rt * 64 + m * 16 + g * 4;
#pragma unroll
        for (int r = 0; r < 4; ++r)
          dp[((size_t)bh * KSEL + row0 + r) * HDIM + col] = f2bf(acc[m][n][r]);
      }
    }
  }
}

// ---------------- K4: MFMA flash attention; K/V staged via global_load_lds ----------------
__global__ __launch_bounds__(256) void k_attn_mfma(const short* __restrict__ q_s,
    const short* __restrict__ k_s, const short* __restrict__ v_t,
    short* __restrict__ out_s) {
  __shared__ __align__(16) short Ks[64 * 128];    // [key][dim], chunk^=(key&7)
  __shared__ __align__(16) short Vt[128 * 64];    // [dim][key], chunk^=(dim&7)
  __shared__ __align__(16) short Pl[4 * 16 * 72]; // per-wave P tile, pad 72
  const int bh = blockIdx.x, qt = blockIdx.y;
  const int tid = threadIdx.x;
  const int w = tid >> 6, lane = tid & 63;
  const int g = lane >> 4, r15 = lane & 15;
  const size_t bhbase = (size_t)bh * KSEL * HDIM;
  const int r0 = qt * 64;
  const float scale = 0.08838834764831845f;  // 1/sqrt(128)

  short8 qf[4];
  {
    const short* qrow = q_s + bhbase + (size_t)(r0 + w * 16 + r15) * HDIM;
#pragma unroll
    for (int ks = 0; ks < 4; ++ks)
      qf[ks] = *(const short8*)(qrow + ks * 32 + g * 8);
  }
  f32x4 o[8];
#pragma unroll
  for (int n = 0; n < 8; ++n) o[n] = (f32x4){0.f, 0.f, 0.f, 0.f};
  float mrow[4] = {-INFINITY, -INFINITY, -INFINITY, -INFINITY};
  float lrow[4] = {0.f, 0.f, 0.f, 0.f};

  short* myP = &Pl[w * 16 * 72];
  const int kl16 = lane >> 4, ks16 = lane & 15;  // K stage lane map: 4 rows/instr
  const int vl8 = lane >> 3, vs8 = lane & 7;     // V stage lane map: 8 dims/instr

  for (int kt = 0; kt <= qt; ++kt) {
    int l0 = kt * 64;
    __syncthreads();
    {
#pragma unroll
      for (int t = 0; t < 4; ++t) {
        int gi = w * 4 + t;
        int kr0 = gi * 4;
        int key = kr0 + kl16;
        const short* ksrc = k_s + bhbase + (size_t)(l0 + key) * HDIM + ((ks16 ^ (key & 7)) << 3);
        gload16(ksrc, &Ks[kr0 * 128]);
        int d0 = gi * 8;
        int d = d0 + vl8;
        const short* vsrc = v_t + ((size_t)bh * HDIM + d) * KSEL + l0 + ((vs8 ^ (d & 7)) << 3);
        gload16(vsrc, &Vt[d0 * 64]);
      }
    }
    __syncthreads();

    f32x4 s[4];
#pragma unroll
    for (int n = 0; n < 4; ++n) s[n] = (f32x4){0.f, 0.f, 0.f, 0.f};
#pragma unroll
    for (int ks = 0; ks < 4; ++ks) {
#pragma unroll
      for (int n = 0; n < 4; ++n) {
        int row = n * 16 + r15;
        short8 kf = *(const short8*)&Ks[row * 128 + ((ks * 4 + g) ^ (r15 & 7)) * 8];
        s[n] = __builtin_amdgcn_mfma_f32_16x16x32_bf16(qf[ks], kf, s[n], 0, 0, 0);
      }
    }

    const bool diag = (kt == qt);
    float sv[4][4];
#pragma unroll
    for (int n = 0; n < 4; ++n) {
      int key = kt * 64 + n * 16 + r15;
#pragma unroll
      for (int r = 0; r < 4; ++r) {
        float xv = s[n][r] * scale;
        int qrow = r0 + w * 16 + g * 4 + r;
        sv[n][r] = (diag && key > qrow) ? -INFINITY : xv;
      }
    }
    float corr[4];
#pragma unroll
    for (int r = 0; r < 4; ++r) {
      float tm = fmaxf(fmaxf(sv[0][r], sv[1][r]), fmaxf(sv[2][r], sv[3][r]));
#pragma unroll
      for (int off = 8; off; off >>= 1) tm = fmaxf(tm, __shfl_xor(tm, off));
      float newm = fmaxf(mrow[r], tm);
      corr[r] = __expf(mrow[r] - newm);
      mrow[r] = newm;
      float ps = 0.f;
#pragma unroll
      for (int n = 0; n < 4; ++n) {
        float pv = __expf(sv[n][r] - newm);
        sv[n][r] = pv;
        ps += pv;
      }
#pragma unroll
      for (int off = 8; off; off >>= 1) ps += __shfl_xor(ps, off);
      lrow[r] = lrow[r] * corr[r] + ps;
    }
    f32x4 corrv = {corr[0], corr[1], corr[2], corr[3]};
#pragma unroll
    for (int n = 0; n < 4; ++n)
#pragma unroll
      for (int r = 0; r < 4; ++r)
        myP[(g * 4 + r) * 72 + n * 16 + r15] = f2bf(sv[n][r]);
#pragma unroll
    for (int n = 0; n < 8; ++n) o[n] *= corrv;

    short8 pf[2];
#pragma unroll
    for (int ks = 0; ks < 2; ++ks)
      pf[ks] = *(const short8*)&myP[r15 * 72 + ks * 32 + g * 8];
#pragma unroll
    for (int ks = 0; ks < 2; ++ks)
#pragma unroll
      for (int n2 = 0; n2 < 8; ++n2) {
        int row = n2 * 16 + r15;
        short8 vf = *(const short8*)&Vt[row * 64 + ((ks * 4 + g) ^ (r15 & 7)) * 8];
        o[n2] = __builtin_amdgcn_mfma_f32_16x16x32_bf16(pf[ks], vf, o[n2], 0, 0, 0);
      }
  }

  float inv[4];
#pragma unroll
  for (int r = 0; r < 4; ++r) inv[r] = 1.f / lrow[r];
#pragma unroll
  for (int n2 = 0; n2 < 8; ++n2) {
#pragma unroll
    for (int r = 0; r < 4; ++r) {
      int qrow = r0 + w * 16 + g * 4 + r;
      out_s[bhbase + (size_t)qrow * HDIM + n2 * 16 + r15] = f2bf(o[n2][r] * inv[r]);
    }
  }
}

// ---------------- K5a: build inverse map inv[bh][t] = k or -1 ----------------
__global__ __launch_bounds__(512) void k_build_inv(const int* __restrict__ idx,
                                                   int* __restrict__ inv) {
  int bh = blockIdx.x, tid = threadIdx.x;
  int* row = inv + (size_t)bh * TT;
  for (int i = tid; i < TT; i += 512) row[i] = -1;
  __syncthreads();
  row[idx[bh * KSEL + tid]] = tid;
}

// ---------------- K5b phase 1: P[h,k,c] = out_s_h @ wo_h^T; both operands async-staged ----------------
__global__ __launch_bounds__(256) void k_oproj_p1(
    const short* __restrict__ out_s_b, const short* __restrict__ wob,
    short* __restrict__ P) {
  __shared__ __align__(16) short As[128 * 64];
  __shared__ __align__(16) short Bs[128 * 64];
  const int h = blockIdx.x, rt = blockIdx.y, ct = blockIdx.z;
  const int tid = threadIdx.x;
  const int lane = tid & 63, wid = tid >> 6;
  const int wr = wid >> 1, wc = wid & 1;
  const int l8 = lane >> 3, s8 = lane & 7;
  f32x4 acc[4][4];
#pragma unroll
  for (int m = 0; m < 4; ++m)
#pragma unroll
    for (int n = 0; n < 4; ++n) acc[m][n] = (f32x4){0.f, 0.f, 0.f, 0.f};
  const int r15 = lane & 15, g = lane >> 4;
#pragma unroll
  for (int k0 = 0; k0 < HDIM; k0 += 64) {
    __syncthreads();
    {
#pragma unroll
      for (int t = 0; t < 4; ++t) {
        int gi = wid * 4 + t;
        int r0 = gi * 8;
        int row = r0 + l8;
        const short* asrc = out_s_b + ((size_t)h * KSEL + rt * 128 + row) * HDIM + k0
                          + ((s8 ^ (row & 7)) << 3);
        gload16(asrc, &As[r0 * 64]);
        const short* bsrc = wob + ((size_t)(ct * 128 + row)) * DD + h * HDIM + k0
                          + ((s8 ^ (row & 7)) << 3);
        gload16(bsrc, &Bs[r0 * 64]);
      }
    }
    __syncthreads();
#pragma unroll
    for (int ks = 0; ks < 2; ++ks) {
      short8 af[4], bfr[4];
#pragma unroll
      for (int m = 0; m < 4; ++m) {
        int row = wr * 64 + m * 16 + r15;
        int chunk = (ks * 4 + g) ^ (row & 7);
        af[m] = *(const short8*)&As[row * 64 + chunk * 8];
      }
#pragma unroll
      for (int n = 0; n < 4; ++n) {
        int col = wc * 64 + n * 16 + r15;
        int chunk = (ks * 4 + g) ^ (col & 7);
        bfr[n] = *(const short8*)&Bs[col * 64 + chunk * 8];
      }
#pragma unroll
      for (int m = 0; m < 4; ++m)
#pragma unroll
        for (int n = 0; n < 4; ++n)
          acc[m][n] = __builtin_amdgcn_mfma_f32_16x16x32_bf16(af[m], bfr[n], acc[m][n], 0, 0, 0);
    }
  }
#pragma unroll
  for (int m = 0; m < 4; ++m) {
#pragma unroll
    for (int r = 0; r < 4; ++r) {
      int row = rt * 128 + wr * 64 + m * 16 + g * 4 + r;
#pragma unroll
      for (int n = 0; n < 4; ++n) {
        int col = ct * 128 + wc * 64 + n * 16 + r15;
        P[((size_t)h * KSEL + row) * DD + col] = f2bf(acc[m][n][r]);
      }
    }
  }
}

// ---------------- K5c phase 2: per-token gather-reduce over heads, write once ----------------
__global__ __launch_bounds__(256) void k_oproj_p2(const short* __restrict__ P,
    const int* __restrict__ inv_b, float* __restrict__ out_b) {
  const int t = blockIdx.x, tid = threadIdx.x;
  const int c0 = tid * 8;
  float acc[8] = {0.f, 0.f, 0.f, 0.f, 0.f, 0.f, 0.f, 0.f};
#pragma unroll
  for (int h = 0; h < HH; ++h) {
    int k = inv_b[h * TT + t];
    if (k >= 0) {
      short8 pv = *(const short8*)&P[((size_t)h * KSEL + k) * DD + c0];
#pragma unroll
      for (int e = 0; e < 8; ++e) acc[e] += bf2f(pv[e]);
    }
  }
  float4 o0 = {acc[0], acc[1], acc[2], acc[3]};
  float4 o1 = {acc[4], acc[5], acc[6], acc[7]};
  *(float4*)&out_b[(size_t)t * DD + c0] = o0;
  *(float4*)&out_b[(size_t)t * DD + c0 + 4] = o1;
}

extern "C" void kernel_launch(void* const* d_in, const int* in_sizes, int n_in,
                              void* d_out, int out_size, void* d_ws, size_t ws_size,
                              hipStream_t stream) {
  (void)in_sizes; (void)n_in; (void)out_size; (void)ws_size;
  const float* x  = (const float*)d_in[0];
  const float* wq = (const float*)d_in[1];
  const float* wk = (const float*)d_in[2];
  const float* wv = (const float*)d_in[3];
  const float* wo = (const float*)d_in[4];
  const float* wr = (const float*)d_in[5];
  float* out = (float*)d_out;

  // workspace layout (~74 MB); P aliases q_s/k_s/v_t (dead after attn);
  // router partials alias P region too (dead before qkv writes it).
  char* ws = (char*)d_ws;
  float* scores = (float*)ws;                                  // 1 MB
  int*   idx    = (int*)(ws + 1048576);                        // 128 KB
  short* wqb    = (short*)(ws + 1179648);                      // 4x 8 MB bf16 weights
  short* wkb    = wqb + 4194304;
  short* wvb    = wkb + 4194304;
  short* wob    = wvb + 4194304;
  short* out_s  = wob + 4194304;                               // 8 MB
  int*   inv    = (int*)((char*)out_s + 8388608);              // 1 MB
  short* P      = (short*)((char*)inv + 1048576);              // 32 MB (per-b reuse)
  short* q_s    = P;
  short* k_s    = P + 4194304;
  short* v_t    = P + 8388608;
  float* part   = (float*)P;                                   // 4 MB (router partials)

  k_cvt_w<<<dim3(2048, 4), 256, 0, stream>>>(wq, wk, wv, wo, wqb);
  k_router2<<<dim3(64, 4), 256, 0, stream>>>(x, wr, part);
  k_router_sum<<<256, 256, 0, stream>>>(part, scores);
  k_topk<<<NBH, 512, 0, stream>>>(scores, idx);
  k_qkv_mfma<<<512, 256, 0, stream>>>(x, wqb, wkb, wvb, idx, q_s, k_s, v_t);
  k_attn_mfma<<<dim3(NBH, KSEL / 64), 256, 0, stream>>>(q_s, k_s, v_t, out_s);
  k_build_inv<<<NBH, 512, 0, stream>>>(idx, inv);
  for (int b = 0; b < BB; ++b) {
    k_oproj_p1<<<dim3(HH, KSEL / 128, DD / 128), 256, 0, stream>>>(
        out_s + (size_t)b * HH * KSEL * HDIM, wob, P);
    k_oproj_p2<<<TT, 256, 0, stream>>>(
        P, inv + (size_t)b * HH * TT, out + (size_t)b * TT * DD);
  }
}

// Round 8
// 294.751 us; speedup vs baseline: 10.1327x; 1.3217x over previous
//
#include <hip/hip_runtime.h>
#include <math.h>

#define BB 4
#define TT 4096
#define DD 2048
#define HH 16
#define HDIM 128
#define KSEL 512
#define NBH (BB*HH)

using short8  = __attribute__((ext_vector_type(8))) short;
using short4v = __attribute__((ext_vector_type(4))) short;
using f32x4   = __attribute__((ext_vector_type(4))) float;

__device__ __forceinline__ short f2bf(float f) {
  unsigned u = __float_as_uint(f);
  u += 0x7fffu + ((u >> 16) & 1u);   // round-nearest-even
  return (short)(u >> 16);
}
__device__ __forceinline__ float bf2f(short s) {
  return __uint_as_float(((unsigned)(unsigned short)s) << 16);
}

// async global->LDS, 16B per lane; LDS dest wave-uniform base + lane*16
__device__ __forceinline__ void gload16(const short* g, short* l) {
  __builtin_amdgcn_global_load_lds(
      (const __attribute__((address_space(1))) void*)g,
      (__attribute__((address_space(3))) void*)l, 16, 0, 0);
}

// ---------------- K0: one-time f32->bf16 weight conversion ----------------
__global__ __launch_bounds__(256) void k_cvt_w(const float* __restrict__ wq,
    const float* __restrict__ wk, const float* __restrict__ wv,
    const float* __restrict__ wo, short* __restrict__ dst) {
  const int wsel = blockIdx.y;
  const float* s = (wsel == 0) ? wq : (wsel == 1) ? wk : (wsel == 2) ? wv : wo;
  size_t base = (size_t)blockIdx.x * 2048 + (size_t)threadIdx.x * 8;
  float4 a = *(const float4*)(s + base);
  float4 b = *(const float4*)(s + base + 4);
  short8 o;
  o[0] = f2bf(a.x); o[1] = f2bf(a.y); o[2] = f2bf(a.z); o[3] = f2bf(a.w);
  o[4] = f2bf(b.x); o[5] = f2bf(b.y); o[6] = f2bf(b.z); o[7] = f2bf(b.w);
  *(short8*)&dst[(size_t)wsel * 4194304 + base] = o;
}

// ---------------- K1: router scores via LDS-tiled split-K f32 GEMM ----------------
__global__ __launch_bounds__(256) void k_router2(const float* __restrict__ x,
    const float* __restrict__ wr, float* __restrict__ part) {
  __shared__ __align__(16) float Xs[256][36];
  __shared__ __align__(16) float Ws[16][36];
  const int tb = blockIdx.x, kq = blockIdx.y;
  const int tid = threadIdx.x;
  const int row0 = tb * 256;
  const int tq = tid >> 2;       // 0..63
  const int hq = tid & 3;
  float acc[4][4];
#pragma unroll
  for (int i = 0; i < 4; ++i)
#pragma unroll
    for (int j = 0; j < 4; ++j) acc[i][j] = 0.f;
  const int srr = tid >> 3, scc = (tid & 7) * 4;
  for (int c = 0; c < 16; ++c) {
    const int k0 = kq * 512 + c * 32;
    __syncthreads();
    {
#pragma unroll
      for (int i = 0; i < 8; ++i) {
        int r = srr + i * 32;
        float4 v = *(const float4*)(x + (size_t)(row0 + r) * DD + k0 + scc);
        *(float4*)&Xs[r][scc] = v;
      }
      if (tid < 128) {
        float4 v = *(const float4*)(wr + (size_t)(tid >> 3) * DD + k0 + (tid & 7) * 4);
        *(float4*)&Ws[tid >> 3][(tid & 7) * 4] = v;
      }
    }
    __syncthreads();
#pragma unroll
    for (int k4 = 0; k4 < 8; ++k4) {
      float4 xv[4], wv[4];
#pragma unroll
      for (int i = 0; i < 4; ++i) xv[i] = *(const float4*)&Xs[tq + i * 64][k4 * 4];
#pragma unroll
      for (int j = 0; j < 4; ++j) wv[j] = *(const float4*)&Ws[hq + j * 4][k4 * 4];
#pragma unroll
      for (int i = 0; i < 4; ++i)
#pragma unroll
        for (int j = 0; j < 4; ++j)
          acc[i][j] += xv[i].x * wv[j].x + xv[i].y * wv[j].y +
                       xv[i].z * wv[j].z + xv[i].w * wv[j].w;
    }
  }
#pragma unroll
  for (int i = 0; i < 4; ++i) {
    int tg = row0 + tq + i * 64;
    int b = tg >> 12, t = tg & (TT - 1);
#pragma unroll
    for (int j = 0; j < 4; ++j)
      part[((size_t)kq * NBH + (b * HH + hq + j * 4)) * TT + t] = acc[i][j];
  }
}

__global__ __launch_bounds__(256) void k_router_sum(const float* __restrict__ part,
                                                    float* __restrict__ scores) {
  size_t i = ((size_t)blockIdx.x * 256 + threadIdx.x) * 4;
  const size_t S = (size_t)NBH * TT;
  float4 a = *(const float4*)(part + i);
  float4 b = *(const float4*)(part + S + i);
  float4 c = *(const float4*)(part + 2 * S + i);
  float4 d = *(const float4*)(part + 3 * S + i);
  float4 o = {((a.x + b.x) + c.x) + d.x, ((a.y + b.y) + c.y) + d.y,
              ((a.z + b.z) + c.z) + d.z, ((a.w + b.w) + c.w) + d.w};
  *(float4*)(scores + i) = o;
}

// ---------------- K2: per-(b,h) top-512 via exact radix-select; fused inverse map ----------------
// Selected set == top-512 by (score, lower-index-first), emitted ascending by position.
// Also writes inv[bh][t] = output slot k (or -1), replacing k_build_inv.
__global__ __launch_bounds__(512) void k_topk(const float* __restrict__ scores,
                                              int* __restrict__ idx,
                                              int* __restrict__ inv) {
  __shared__ unsigned hist[256];
  __shared__ unsigned ssum[257];
  __shared__ unsigned wtot[8];
  __shared__ unsigned sh_b;
  const int bh = blockIdx.x, tid = threadIdx.x;
  const int lane = tid & 63, wv = tid >> 6;
  const float* sc = scores + (size_t)bh * TT;
  unsigned key[8];
  {
    float4 v0 = *(const float4*)(sc + tid * 8);
    float4 v1 = *(const float4*)(sc + tid * 8 + 4);
    float vs[8] = {v0.x, v0.y, v0.z, v0.w, v1.x, v1.y, v1.z, v1.w};
#pragma unroll
    for (int i = 0; i < 8; ++i) {
      unsigned u = __float_as_uint(vs[i]);
      key[i] = (u & 0x80000000u) ? ~u : (u | 0x80000000u);  // monotone map
    }
  }
  unsigned prefix = 0, need = KSEL;
  for (int shift = 24; shift >= 0; shift -= 8) {
    if (tid < 256) hist[tid] = 0;
    __syncthreads();
#pragma unroll
    for (int i = 0; i < 8; ++i) {
      bool m = (shift == 24) || ((key[i] >> (shift + 8)) == prefix);
      if (m) atomicAdd(&hist[(key[i] >> shift) & 255], 1u);
    }
    __syncthreads();
    if (wv == 0) {   // wave0: suffix sums of 256 bins, 4 bins/lane, shuffle scan
      unsigned v0 = hist[lane * 4], v1 = hist[lane * 4 + 1];
      unsigned v2 = hist[lane * 4 + 2], v3 = hist[lane * 4 + 3];
      unsigned s3 = v3, s2 = v2 + s3, s1 = v1 + s2, s0 = v0 + s1;
      unsigned t = s0;
#pragma unroll
      for (int off = 1; off < 64; off <<= 1) {
        unsigned o = __shfl_down(t, off);
        if (lane + off < 64) t += o;
      }
      unsigned above = t - s0;
      ssum[lane * 4]     = s0 + above;
      ssum[lane * 4 + 1] = s1 + above;
      ssum[lane * 4 + 2] = s2 + above;
      ssum[lane * 4 + 3] = s3 + above;
      if (lane == 0) ssum[256] = 0;
    }
    __syncthreads();
    if (tid < 256) {
      if (ssum[tid] >= need && ssum[tid + 1] < need) sh_b = (unsigned)tid;
    }
    __syncthreads();
    unsigned bstar = sh_b;
    need -= ssum[bstar + 1];                // strictly-greater at this digit
    prefix = (shift == 24) ? bstar : ((prefix << 8) | bstar);
  }
  // compaction: sel = key>thr  OR  (key==thr AND tie-rank<need, lowest index first)
  const unsigned thr = prefix;
  unsigned cgt = 0, ceq = 0;
#pragma unroll
  for (int i = 0; i < 8; ++i) { cgt += (key[i] > thr); ceq += (key[i] == thr); }
  unsigned packed = (cgt << 16) | ceq;
  unsigned inc = packed;
#pragma unroll
  for (int off = 1; off < 64; off <<= 1) {
    unsigned o = __shfl_up(inc, off);
    if (lane >= off) inc += o;
  }
  if (lane == 63) wtot[wv] = inc;
  __syncthreads();
  unsigned wbase = 0;
#pragma unroll
  for (int w2 = 0; w2 < 8; ++w2) wbase += (w2 < wv) ? wtot[w2] : 0u;
  unsigned base = wbase + inc - packed;     // exclusive prefix (packed)
  unsigned gt_before = base >> 16, eq_before = base & 0xffffu;
  int* op = idx + bh * KSEL;
  int* invrow = inv + (size_t)bh * TT;
#pragma unroll
  for (int i = 0; i < 8; ++i) {
    bool isgt = key[i] > thr, iseq = key[i] == thr;
    bool sel = isgt || (iseq && eq_before < need);
    int pos = -1;
    if (sel) {
      pos = (int)(gt_before + (eq_before < need ? eq_before : need));
      op[pos] = tid * 8 + i;
    }
    invrow[tid * 8 + i] = pos;
    gt_before += isgt; eq_before += iseq;
  }
}

// ---------------- K3: merged gathered QKV projection via bf16 MFMA ----------------
// B staged via global_load_lds (pre-swizzled source); A reg-staged (f32->bf16 cvt).
__global__ __launch_bounds__(256, 2) void k_qkv_mfma(
    const float* __restrict__ x, const short* __restrict__ wqb,
    const short* __restrict__ wkb, const short* __restrict__ wvb,
    const int* __restrict__ idx,
    short* __restrict__ q_s, short* __restrict__ k_s, short* __restrict__ v_t) {
  __shared__ __align__(16) short As[64 * 64];
  __shared__ __align__(16) short Bs[3][128 * 64];
  __shared__ int tIdx[64];
  const int L = blockIdx.x;
  const int bh = (L & 7) * 8 + (L >> 6);
  const int rt = (L >> 3) & 7;
  const int b = bh >> 4, h = bh & 15;
  const int tid = threadIdx.x;
  if (tid < 64) tIdx[tid] = idx[bh * KSEL + rt * 64 + tid];
  __syncthreads();
  const int lane = tid & 63, w = tid >> 6;
  const int g = lane >> 4, r15 = lane & 15;
  const int arow = tid >> 2, kq = tid & 3;       // A stage: 4 thr/row, 16 k each
  const int lcol8 = lane >> 3, lslot = lane & 7; // B stage lane mapping
  const float* aPtr = x + ((size_t)b * TT + tIdx[arow]) * DD + kq * 16;
  f32x4 acc[4][6];
#pragma unroll
  for (int m = 0; m < 4; ++m)
#pragma unroll
    for (int n = 0; n < 6; ++n) acc[m][n] = (f32x4){0.f, 0.f, 0.f, 0.f};
  const int rm = arow & 7;
  for (int k0 = 0; k0 < DD; k0 += 64) {
    __syncthreads();
    {
      // A: reg-stage + cvt + swizzled ds_write
      float4 a0 = *(const float4*)(aPtr + k0);
      float4 a1 = *(const float4*)(aPtr + k0 + 4);
      float4 a2 = *(const float4*)(aPtr + k0 + 8);
      float4 a3 = *(const float4*)(aPtr + k0 + 12);
      short8 p0, p1;
      p0[0] = f2bf(a0.x); p0[1] = f2bf(a0.y); p0[2] = f2bf(a0.z); p0[3] = f2bf(a0.w);
      p0[4] = f2bf(a1.x); p0[5] = f2bf(a1.y); p0[6] = f2bf(a1.z); p0[7] = f2bf(a1.w);
      p1[0] = f2bf(a2.x); p1[1] = f2bf(a2.y); p1[2] = f2bf(a2.z); p1[3] = f2bf(a2.w);
      p1[4] = f2bf(a3.x); p1[5] = f2bf(a3.y); p1[6] = f2bf(a3.z); p1[7] = f2bf(a3.w);
      *(short8*)&As[arow * 64 + ((2 * kq) ^ rm) * 8] = p0;
      *(short8*)&As[arow * 64 + ((2 * kq + 1) ^ rm) * 8] = p1;
      // B: async global->LDS, linear dest + inverse-swizzled source
#pragma unroll
      for (int t = 0; t < 12; ++t) {
        int gi = w * 12 + t;
        int p = gi >> 4;
        int c0 = (gi & 15) << 3;
        int col = c0 + lcol8;
        const short* wsrc = (p == 0 ? wqb : p == 1 ? wkb : wvb)
                          + ((size_t)(h * HDIM + col)) * DD + k0 + ((lslot ^ (col & 7)) << 3);
        gload16(wsrc, &Bs[p][c0 * 64]);
      }
    }
    __syncthreads();
#pragma unroll
    for (int ks = 0; ks < 2; ++ks) {
      short8 af[4], bfr[6];
#pragma unroll
      for (int m = 0; m < 4; ++m) {
        int row = m * 16 + r15;
        af[m] = *(const short8*)&As[row * 64 + ((ks * 4 + g) ^ (row & 7)) * 8];
      }
#pragma unroll
      for (int n = 0; n < 6; ++n) {
        int nf = w * 6 + n;
        int colr = (nf & 7) * 16 + r15;
        bfr[n] = *(const short8*)&Bs[nf >> 3][colr * 64 + ((ks * 4 + g) ^ (colr & 7)) * 8];
      }
#pragma unroll
      for (int m = 0; m < 4; ++m)
#pragma unroll
        for (int n = 0; n < 6; ++n)
          acc[m][n] = __builtin_amdgcn_mfma_f32_16x16x32_bf16(af[m], bfr[n], acc[m][n], 0, 0, 0);
    }
  }
#pragma unroll
  for (int n = 0; n < 6; ++n) {
    int nf = w * 6 + n;
    int p = nf >> 3;
    int col = (nf & 7) * 16 + r15;
    if (p == 2) {
#pragma unroll
      for (int m = 0; m < 4; ++m) {
        short4v pk;
#pragma unroll
        for (int r = 0; r < 4; ++r) pk[r] = f2bf(acc[m][n][r]);
        *(short4v*)&v_t[((size_t)bh * HDIM + col) * KSEL + rt * 64 + m * 16 + g * 4] = pk;
      }
    } else {
      short* dp = (p == 0) ? q_s : k_s;
#pragma unroll
      for (int m = 0; m < 4; ++m) {
        int row0 = rt * 64 + m * 16 + g * 4;
#pragma unroll
        for (int r = 0; r < 4; ++r)
          dp[((size_t)bh * KSEL + row0 + r) * HDIM + col] = f2bf(acc[m][n][r]);
      }
    }
  }
}

// ---------------- K4: MFMA flash attention; K/V staged via global_load_lds ----------------
__global__ __launch_bounds__(256) void k_attn_mfma(const short* __restrict__ q_s,
    const short* __restrict__ k_s, const short* __restrict__ v_t,
    short* __restrict__ out_s) {
  __shared__ __align__(16) short Ks[64 * 128];    // [key][dim], chunk^=(key&7)
  __shared__ __align__(16) short Vt[128 * 64];    // [dim][key], chunk^=(dim&7)
  __shared__ __align__(16) short Pl[4 * 16 * 72]; // per-wave P tile, pad 72
  const int bh = blockIdx.x, qt = blockIdx.y;
  const int tid = threadIdx.x;
  const int w = tid >> 6, lane = tid & 63;
  const int g = lane >> 4, r15 = lane & 15;
  const size_t bhbase = (size_t)bh * KSEL * HDIM;
  const int r0 = qt * 64;
  const float scale = 0.08838834764831845f;  // 1/sqrt(128)

  short8 qf[4];
  {
    const short* qrow = q_s + bhbase + (size_t)(r0 + w * 16 + r15) * HDIM;
#pragma unroll
    for (int ks = 0; ks < 4; ++ks)
      qf[ks] = *(const short8*)(qrow + ks * 32 + g * 8);
  }
  f32x4 o[8];
#pragma unroll
  for (int n = 0; n < 8; ++n) o[n] = (f32x4){0.f, 0.f, 0.f, 0.f};
  float mrow[4] = {-INFINITY, -INFINITY, -INFINITY, -INFINITY};
  float lrow[4] = {0.f, 0.f, 0.f, 0.f};

  short* myP = &Pl[w * 16 * 72];
  const int kl16 = lane >> 4, ks16 = lane & 15;  // K stage lane map: 4 rows/instr
  const int vl8 = lane >> 3, vs8 = lane & 7;     // V stage lane map: 8 dims/instr

  for (int kt = 0; kt <= qt; ++kt) {
    int l0 = kt * 64;
    __syncthreads();
    {
#pragma unroll
      for (int t = 0; t < 4; ++t) {
        int gi = w * 4 + t;
        int kr0 = gi * 4;
        int key = kr0 + kl16;
        const short* ksrc = k_s + bhbase + (size_t)(l0 + key) * HDIM + ((ks16 ^ (key & 7)) << 3);
        gload16(ksrc, &Ks[kr0 * 128]);
        int d0 = gi * 8;
        int d = d0 + vl8;
        const short* vsrc = v_t + ((size_t)bh * HDIM + d) * KSEL + l0 + ((vs8 ^ (d & 7)) << 3);
        gload16(vsrc, &Vt[d0 * 64]);
      }
    }
    __syncthreads();

    f32x4 s[4];
#pragma unroll
    for (int n = 0; n < 4; ++n) s[n] = (f32x4){0.f, 0.f, 0.f, 0.f};
#pragma unroll
    for (int ks = 0; ks < 4; ++ks) {
#pragma unroll
      for (int n = 0; n < 4; ++n) {
        int row = n * 16 + r15;
        short8 kf = *(const short8*)&Ks[row * 128 + ((ks * 4 + g) ^ (r15 & 7)) * 8];
        s[n] = __builtin_amdgcn_mfma_f32_16x16x32_bf16(qf[ks], kf, s[n], 0, 0, 0);
      }
    }

    const bool diag = (kt == qt);
    float sv[4][4];
#pragma unroll
    for (int n = 0; n < 4; ++n) {
      int key = kt * 64 + n * 16 + r15;
#pragma unroll
      for (int r = 0; r < 4; ++r) {
        float xv = s[n][r] * scale;
        int qrow = r0 + w * 16 + g * 4 + r;
        sv[n][r] = (diag && key > qrow) ? -INFINITY : xv;
      }
    }
    float corr[4];
#pragma unroll
    for (int r = 0; r < 4; ++r) {
      float tm = fmaxf(fmaxf(sv[0][r], sv[1][r]), fmaxf(sv[2][r], sv[3][r]));
#pragma unroll
      for (int off = 8; off; off >>= 1) tm = fmaxf(tm, __shfl_xor(tm, off));
      float newm = fmaxf(mrow[r], tm);
      corr[r] = __expf(mrow[r] - newm);
      mrow[r] = newm;
      float ps = 0.f;
#pragma unroll
      for (int n = 0; n < 4; ++n) {
        float pv = __expf(sv[n][r] - newm);
        sv[n][r] = pv;
        ps += pv;
      }
#pragma unroll
      for (int off = 8; off; off >>= 1) ps += __shfl_xor(ps, off);
      lrow[r] = lrow[r] * corr[r] + ps;
    }
    f32x4 corrv = {corr[0], corr[1], corr[2], corr[3]};
#pragma unroll
    for (int n = 0; n < 4; ++n)
#pragma unroll
      for (int r = 0; r < 4; ++r)
        myP[(g * 4 + r) * 72 + n * 16 + r15] = f2bf(sv[n][r]);
#pragma unroll
    for (int n = 0; n < 8; ++n) o[n] *= corrv;

    short8 pf[2];
#pragma unroll
    for (int ks = 0; ks < 2; ++ks)
      pf[ks] = *(const short8*)&myP[r15 * 72 + ks * 32 + g * 8];
#pragma unroll
    for (int ks = 0; ks < 2; ++ks)
#pragma unroll
      for (int n2 = 0; n2 < 8; ++n2) {
        int row = n2 * 16 + r15;
        short8 vf = *(const short8*)&Vt[row * 64 + ((ks * 4 + g) ^ (r15 & 7)) * 8];
        o[n2] = __builtin_amdgcn_mfma_f32_16x16x32_bf16(pf[ks], vf, o[n2], 0, 0, 0);
      }
  }

  float inv[4];
#pragma unroll
  for (int r = 0; r < 4; ++r) inv[r] = 1.f / lrow[r];
#pragma unroll
  for (int n2 = 0; n2 < 8; ++n2) {
#pragma unroll
    for (int r = 0; r < 4; ++r) {
      int qrow = r0 + w * 16 + g * 4 + r;
      out_s[bhbase + (size_t)qrow * HDIM + n2 * 16 + r15] = f2bf(o[n2][r] * inv[r]);
    }
  }
}

// ---------------- K5b phase 1: P[h,k,c] = out_s_h @ wo_h^T; both operands async-staged ----------------
__global__ __launch_bounds__(256) void k_oproj_p1(
    const short* __restrict__ out_s_b, const short* __restrict__ wob,
    short* __restrict__ P) {
  __shared__ __align__(16) short As[128 * 64];
  __shared__ __align__(16) short Bs[128 * 64];
  const int h = blockIdx.x, rt = blockIdx.y, ct = blockIdx.z;
  const int tid = threadIdx.x;
  const int lane = tid & 63, wid = tid >> 6;
  const int wr = wid >> 1, wc = wid & 1;
  const int l8 = lane >> 3, s8 = lane & 7;
  f32x4 acc[4][4];
#pragma unroll
  for (int m = 0; m < 4; ++m)
#pragma unroll
    for (int n = 0; n < 4; ++n) acc[m][n] = (f32x4){0.f, 0.f, 0.f, 0.f};
  const int r15 = lane & 15, g = lane >> 4;
#pragma unroll
  for (int k0 = 0; k0 < HDIM; k0 += 64) {
    __syncthreads();
    {
#pragma unroll
      for (int t = 0; t < 4; ++t) {
        int gi = wid * 4 + t;
        int r0 = gi * 8;
        int row = r0 + l8;
        const short* asrc = out_s_b + ((size_t)h * KSEL + rt * 128 + row) * HDIM + k0
                          + ((s8 ^ (row & 7)) << 3);
        gload16(asrc, &As[r0 * 64]);
        const short* bsrc = wob + ((size_t)(ct * 128 + row)) * DD + h * HDIM + k0
                          + ((s8 ^ (row & 7)) << 3);
        gload16(bsrc, &Bs[r0 * 64]);
      }
    }
    __syncthreads();
#pragma unroll
    for (int ks = 0; ks < 2; ++ks) {
      short8 af[4], bfr[4];
#pragma unroll
      for (int m = 0; m < 4; ++m) {
        int row = wr * 64 + m * 16 + r15;
        int chunk = (ks * 4 + g) ^ (row & 7);
        af[m] = *(const short8*)&As[row * 64 + chunk * 8];
      }
#pragma unroll
      for (int n = 0; n < 4; ++n) {
        int col = wc * 64 + n * 16 + r15;
        int chunk = (ks * 4 + g) ^ (col & 7);
        bfr[n] = *(const short8*)&Bs[col * 64 + chunk * 8];
      }
#pragma unroll
      for (int m = 0; m < 4; ++m)
#pragma unroll
        for (int n = 0; n < 4; ++n)
          acc[m][n] = __builtin_amdgcn_mfma_f32_16x16x32_bf16(af[m], bfr[n], acc[m][n], 0, 0, 0);
    }
  }
#pragma unroll
  for (int m = 0; m < 4; ++m) {
#pragma unroll
    for (int r = 0; r < 4; ++r) {
      int row = rt * 128 + wr * 64 + m * 16 + g * 4 + r;
#pragma unroll
      for (int n = 0; n < 4; ++n) {
        int col = ct * 128 + wc * 64 + n * 16 + r15;
        P[((size_t)h * KSEL + row) * DD + col] = f2bf(acc[m][n][r]);
      }
    }
  }
}

// ---------------- K5c phase 2: per-token gather-reduce over heads, write once ----------------
__global__ __launch_bounds__(256) void k_oproj_p2(const short* __restrict__ P,
    const int* __restrict__ inv_b, float* __restrict__ out_b) {
  const int t = blockIdx.x, tid = threadIdx.x;
  const int c0 = tid * 8;
  float acc[8] = {0.f, 0.f, 0.f, 0.f, 0.f, 0.f, 0.f, 0.f};
#pragma unroll
  for (int h = 0; h < HH; ++h) {
    int k = inv_b[h * TT + t];
    if (k >= 0) {
      short8 pv = *(const short8*)&P[((size_t)h * KSEL + k) * DD + c0];
#pragma unroll
      for (int e = 0; e < 8; ++e) acc[e] += bf2f(pv[e]);
    }
  }
  float4 o0 = {acc[0], acc[1], acc[2], acc[3]};
  float4 o1 = {acc[4], acc[5], acc[6], acc[7]};
  *(float4*)&out_b[(size_t)t * DD + c0] = o0;
  *(float4*)&out_b[(size_t)t * DD + c0 + 4] = o1;
}

extern "C" void kernel_launch(void* const* d_in, const int* in_sizes, int n_in,
                              void* d_out, int out_size, void* d_ws, size_t ws_size,
                              hipStream_t stream) {
  (void)in_sizes; (void)n_in; (void)out_size; (void)ws_size;
  const float* x  = (const float*)d_in[0];
  const float* wq = (const float*)d_in[1];
  const float* wk = (const float*)d_in[2];
  const float* wv = (const float*)d_in[3];
  const float* wo = (const float*)d_in[4];
  const float* wr = (const float*)d_in[5];
  float* out = (float*)d_out;

  // workspace layout (~74 MB); P aliases q_s/k_s/v_t (dead after attn);
  // router partials alias P region too (dead before qkv writes it).
  char* ws = (char*)d_ws;
  float* scores = (float*)ws;                                  // 1 MB
  int*   idx    = (int*)(ws + 1048576);                        // 128 KB
  short* wqb    = (short*)(ws + 1179648);                      // 4x 8 MB bf16 weights
  short* wkb    = wqb + 4194304;
  short* wvb    = wkb + 4194304;
  short* wob    = wvb + 4194304;
  short* out_s  = wob + 4194304;                               // 8 MB
  int*   inv    = (int*)((char*)out_s + 8388608);              // 1 MB
  short* P      = (short*)((char*)inv + 1048576);              // 32 MB (per-b reuse)
  short* q_s    = P;
  short* k_s    = P + 4194304;
  short* v_t    = P + 8388608;
  float* part   = (float*)P;                                   // 4 MB (router partials)

  k_cvt_w<<<dim3(2048, 4), 256, 0, stream>>>(wq, wk, wv, wo, wqb);
  k_router2<<<dim3(64, 4), 256, 0, stream>>>(x, wr, part);
  k_router_sum<<<256, 256, 0, stream>>>(part, scores);
  k_topk<<<NBH, 512, 0, stream>>>(scores, idx, inv);
  k_qkv_mfma<<<512, 256, 0, stream>>>(x, wqb, wkb, wvb, idx, q_s, k_s, v_t);
  k_attn_mfma<<<dim3(NBH, KSEL / 64), 256, 0, stream>>>(q_s, k_s, v_t, out_s);
  for (int b = 0; b < BB; ++b) {
    k_oproj_p1<<<dim3(HH, KSEL / 128, DD / 128), 256, 0, stream>>>(
        out_s + (size_t)b * HH * KSEL * HDIM, wob, P);
    k_oproj_p2<<<TT, 256, 0, stream>>>(
        P, inv + (size_t)b * HH * TT, out + (size_t)b * TT * DD);
  }
}